// Round 1
// baseline (2019.684 us; speedup 1.0000x reference)
//
#include <hip/hip_runtime.h>
#include <cmath>

#define NNODES 32768
#define NEDGES 524288
#define NBATCH 16
#define NSAMP  2048
#define NHID   64
#define EPS    1e-5f

struct YArr { float v[192]; };

// ---------------- encoder: h = x @ enc_W + enc_b ----------------
__global__ __launch_bounds__(256) void encoder_kernel(
    const float* __restrict__ x, const float* __restrict__ W,
    const float* __restrict__ b, float* __restrict__ h)
{
  int idx = blockIdx.x * 256 + threadIdx.x;   // n*64 + c
  int n = idx >> 6, c = idx & 63;
  float v = b[c];
  v = fmaf(x[n*3+0], W[0*64+c], v);
  v = fmaf(x[n*3+1], W[1*64+c], v);
  v = fmaf(x[n*3+2], W[2*64+c], v);
  h[idx] = v;
}

// ---------------- two-layer MLP (edge: gather+scatter, node: direct) ----
// Block 256 = 4 waves. Each wave handles 8 rows per iteration.
// lane = output channel. LDS: W1 32KB + W2 16KB + per-wave inputs 16KB = 64KB.
template<int IS_EDGE>
__global__ __launch_bounds__(256) void mlp2_kernel(
    const float* __restrict__ inA, const float* __restrict__ inB,
    const int* __restrict__ src, const int* __restrict__ dst,
    const float* __restrict__ W1, const float* __restrict__ b1,
    const float* __restrict__ W2, const float* __restrict__ b2,
    float* __restrict__ out, int M)
{
  __shared__ float sW1[128*64];
  __shared__ float sW2[64*64];
  __shared__ float sIn[4][8][128];   // per-wave staging; [.. ][0:64) reused for m1

  int tid = threadIdx.x;
  for (int i = tid; i < 128*64; i += 256) sW1[i] = W1[i];
  for (int i = tid; i < 64*64;  i += 256) sW2[i] = W2[i];
  int lane = tid & 63, wave = tid >> 6;
  float bias1 = b1[lane], bias2 = b2[lane];
  __syncthreads();

  float (* const myIn)[128] = sIn[wave];

  for (int base = blockIdx.x * 32; base < M; base += gridDim.x * 32) {
    int e0 = base + wave * 8;
    int rd[8];
    #pragma unroll
    for (int i = 0; i < 8; i++) {
      int e = e0 + i;
      int rA, rB;
      if (IS_EDGE) { rA = dst[e]; rB = src[e]; }   // xi = h[dst], xj = h[src]
      else         { rA = e;      rB = e;      }
      rd[i] = rA;
      myIn[i][lane]      = inA[rA*64 + lane];
      myIn[i][64 + lane] = inB[rB*64 + lane];
    }
    __syncthreads();

    // layer 1: m1[c] = relu(sum_k in[k] * W1[k][c] + b1[c])
    float acc[8];
    #pragma unroll
    for (int i = 0; i < 8; i++) acc[i] = bias1;
    #pragma unroll 8
    for (int k = 0; k < 128; k += 4) {
      float w0 = sW1[(k+0)*64 + lane];
      float w1 = sW1[(k+1)*64 + lane];
      float w2 = sW1[(k+2)*64 + lane];
      float w3 = sW1[(k+3)*64 + lane];
      #pragma unroll
      for (int i = 0; i < 8; i++) {
        float4 xv = *(const float4*)(&myIn[i][k]);
        acc[i] = fmaf(w0, xv.x, acc[i]);
        acc[i] = fmaf(w1, xv.y, acc[i]);
        acc[i] = fmaf(w2, xv.z, acc[i]);
        acc[i] = fmaf(w3, xv.w, acc[i]);
      }
    }
    // write m1 in place (inputs dead now; wave-private buffer)
    #pragma unroll
    for (int i = 0; i < 8; i++) myIn[i][lane] = fmaxf(acc[i], 0.f);
    __syncthreads();

    // layer 2: m2[c] = relu(sum_k m1[k] * W2[k][c] + b2[c])
    float acc2[8];
    #pragma unroll
    for (int i = 0; i < 8; i++) acc2[i] = bias2;
    #pragma unroll 8
    for (int k = 0; k < 64; k += 4) {
      float w0 = sW2[(k+0)*64 + lane];
      float w1 = sW2[(k+1)*64 + lane];
      float w2 = sW2[(k+2)*64 + lane];
      float w3 = sW2[(k+3)*64 + lane];
      #pragma unroll
      for (int i = 0; i < 8; i++) {
        float4 xv = *(const float4*)(&myIn[i][k]);
        acc2[i] = fmaf(w0, xv.x, acc2[i]);
        acc2[i] = fmaf(w1, xv.y, acc2[i]);
        acc2[i] = fmaf(w2, xv.z, acc2[i]);
        acc2[i] = fmaf(w3, xv.w, acc2[i]);
      }
    }
    #pragma unroll
    for (int i = 0; i < 8; i++) {
      float v = fmaxf(acc2[i], 0.f);
      if (IS_EDGE) unsafeAtomicAdd(&out[rd[i]*64 + lane], v);
      else         out[(e0+i)*64 + lane] = v;
    }
    __syncthreads();
  }
}

// ---------------- per-graph InstanceNorm: u -> h ----------------
__global__ __launch_bounds__(1024) void instnorm_kernel(
    const float* __restrict__ u, float* __restrict__ h)
{
  int b = blockIdx.x;
  int c = threadIdx.x & 63, rg = threadIdx.x >> 6;   // 16 row-groups
  const float* ub = u + (size_t)b * NSAMP * 64;
  float s = 0.f, s2 = 0.f;
  for (int i = rg; i < NSAMP; i += 16) {
    float v = ub[i*64 + c];
    s += v; s2 += v*v;
  }
  __shared__ float ps[16][64], ps2[16][64], smean[64], srstd[64];
  ps[rg][c] = s; ps2[rg][c] = s2;
  __syncthreads();
  if (rg == 0) {
    float ts = 0.f, ts2 = 0.f;
    #pragma unroll
    for (int j = 0; j < 16; j++) { ts += ps[j][c]; ts2 += ps2[j][c]; }
    float mean = ts * (1.f / NSAMP);
    float var  = ts2 * (1.f / NSAMP) - mean * mean;
    smean[c] = mean;
    srstd[c] = rsqrtf(var + EPS);
  }
  __syncthreads();
  float mean = smean[c], rstd = srstd[c];
  float* hb = h + (size_t)b * NSAMP * 64;
  for (int i = rg; i < NSAMP; i += 16)
    hb[i*64 + c] = (ub[i*64 + c] - mean) * rstd;
}

// ---------------- decoder + unit normalize: h -> X ----------------
__global__ __launch_bounds__(64) void decoder_kernel(
    const float* __restrict__ h, const float* __restrict__ W,
    const float* __restrict__ b, float* __restrict__ X)
{
  __shared__ float sh[64][65];
  int lane = threadIdx.x;
  int nb = blockIdx.x * 64;
  for (int r = 0; r < 64; r++) sh[r][lane] = h[(size_t)(nb + r) * 64 + lane];
  __syncthreads();
  float a0 = b[0], a1 = b[1], a2 = b[2];
  #pragma unroll
  for (int c = 0; c < 64; c++) {
    float v = sh[lane][c];
    a0 = fmaf(v, W[c*3+0], a0);
    a1 = fmaf(v, W[c*3+1], a1);
    a2 = fmaf(v, W[c*3+2], a2);
  }
  float inv = 1.f / sqrtf(a0*a0 + a1*a1 + a2*a2);
  int n = nb + lane;
  X[n*3+0] = a0 * inv;
  X[n*3+1] = a1 * inv;
  X[n*3+2] = a2 * inv;
}

// ---------------- reductions / MMD ----------------
__device__ inline float block_reduce_sum(float v) {
  #pragma unroll
  for (int o = 32; o > 0; o >>= 1) v += __shfl_down(v, o, 64);
  __shared__ float red[4];
  int lane = threadIdx.x & 63, w = threadIdx.x >> 6;
  if (lane == 0) red[w] = v;
  __syncthreads();
  float t = 0.f;
  if (threadIdx.x == 0) t = red[0] + red[1] + red[2] + red[3];
  return t;
}

__global__ __launch_bounds__(256) void kxx_kernel(
    const float* __restrict__ X, float* __restrict__ kxx)
{
  int b  = blockIdx.x >> 5;   // 16 batches
  int nt = blockIdx.x & 31;   // 32 tiles of 64 n's
  const float* Xb = X + (size_t)b * NSAMP * 3;
  __shared__ float sx[192];
  if (threadIdx.x < 192) sx[threadIdx.x] = Xb[nt*192 + threadIdx.x];
  __syncthreads();
  float ps = 0.f;
  for (int it = 0; it < 8; it++) {
    int m = it*256 + threadIdx.x;
    float x0 = Xb[m*3+0], x1 = Xb[m*3+1], x2 = Xb[m*3+2];
    #pragma unroll
    for (int n = 0; n < 64; n++) {
      float d = x0*sx[n*3+0] + x1*sx[n*3+1] + x2*sx[n*3+2];
      ps += __expf(2.f*d - 2.f);
    }
  }
  float t = block_reduce_sum(ps);
  if (threadIdx.x == 0) atomicAdd(&kxx[b], t);
}

__global__ __launch_bounds__(256) void kxy_kernel(
    const float* __restrict__ X, YArr Y, float* __restrict__ kxy)
{
  int b = blockIdx.x;
  const float* Xb = X + (size_t)b * NSAMP * 3;
  float ps = 0.f;
  for (int it = 0; it < 8; it++) {
    int n = it*256 + threadIdx.x;
    float x0 = Xb[n*3+0], x1 = Xb[n*3+1], x2 = Xb[n*3+2];
    #pragma unroll
    for (int m = 0; m < 64; m++) {
      float d = x0*Y.v[m*3+0] + x1*Y.v[m*3+1] + x2*Y.v[m*3+2];
      ps += __expf(2.f*d - 2.f);
    }
  }
  float t = block_reduce_sum(ps);
  if (threadIdx.x == 0) kxy[b] = t;
}

__global__ void loss_kernel(const float* __restrict__ kxx,
                            const float* __restrict__ kxy,
                            float kyy, float* __restrict__ out)
{
  if (threadIdx.x == 0 && blockIdx.x == 0) {
    float s = 0.f;
    for (int b = 0; b < NBATCH; b++)
      s += kxx[b] * (1.0f/((float)NSAMP*(float)NSAMP))
         - 2.0f * kxy[b] * (1.0f/((float)NSAMP*64.0f));
    out[0] = s * (1.0f/NBATCH) + kyy;
  }
}

// ---------------- launch ----------------
extern "C" void kernel_launch(void* const* d_in, const int* in_sizes, int n_in,
                              void* d_out, int out_size, void* d_ws, size_t ws_size,
                              hipStream_t stream)
{
  const float* x    = (const float*)d_in[0];
  const int*   esrc = (const int*)  d_in[1];
  const int*   edst = (const int*)  d_in[2];
  const float* encW = (const float*)d_in[4];
  const float* encb = (const float*)d_in[5];
  const float* m1W  = (const float*)d_in[6];
  const float* m1b  = (const float*)d_in[7];
  const float* m2W  = (const float*)d_in[8];
  const float* m2b  = (const float*)d_in[9];
  const float* u1W  = (const float*)d_in[10];
  const float* u1b  = (const float*)d_in[11];
  const float* u2W  = (const float*)d_in[12];
  const float* u2b  = (const float*)d_in[13];
  const float* decW = (const float*)d_in[14];
  const float* decb = (const float*)d_in[15];
  float* out = (float*)d_out;

  float* h   = (float*)d_ws;                 // [N,64]
  float* agg = h   + (size_t)NNODES * 64;    // [N,64]
  float* u   = agg + (size_t)NNODES * 64;    // [N,64]
  float* kxx = u   + (size_t)NNODES * 64;    // [16]
  float* kxy = kxx + 16;                     // [16]

  float* X = out + 1;                        // [N,3] lives in d_out

  encoder_kernel<<<NNODES*64/256, 256, 0, stream>>>(x, encW, encb, h);

  for (int l = 0; l < 4; l++) {
    hipMemsetAsync(agg, 0, (size_t)NNODES * 64 * sizeof(float), stream);
    mlp2_kernel<1><<<2048, 256, 0, stream>>>(
        h, h, esrc, edst,
        m1W + (size_t)l*128*64, m1b + l*64,
        m2W + (size_t)l*64*64,  m2b + l*64,
        agg, NEDGES);
    mlp2_kernel<0><<<1024, 256, 0, stream>>>(
        h, agg, nullptr, nullptr,
        u1W + (size_t)l*128*64, u1b + l*64,
        u2W + (size_t)l*64*64,  u2b + l*64,
        u, NNODES);
    instnorm_kernel<<<NBATCH, 1024, 0, stream>>>(u, h);
  }

  decoder_kernel<<<NNODES/64, 64, 0, stream>>>(h, decW, decb, X);

  hipMemsetAsync(kxx, 0, 16 * sizeof(float), stream);
  kxx_kernel<<<NBATCH*32, 256, 0, stream>>>(X, kxx);

  // fibonacci_sphere(64) + kYY on host in double (deterministic, baked into graph)
  YArr Y;
  {
    const double pi = 3.14159265358979323846;
    double phi = pi * (3.0 - sqrt(5.0));
    for (int i = 0; i < 64; i++) {
      double y  = 1.0 - 2.0 * (double)i / 63.0;
      double r  = sqrt(fmax(0.0, 1.0 - y*y));
      double th = phi * (double)i;
      Y.v[i*3+0] = (float)(cos(th) * r);
      Y.v[i*3+1] = (float)y;
      Y.v[i*3+2] = (float)(sin(th) * r);
    }
  }
  double kyy_acc = 0.0;
  for (int i = 0; i < 64; i++)
    for (int j = 0; j < 64; j++) {
      double d = (double)Y.v[i*3+0]*Y.v[j*3+0]
               + (double)Y.v[i*3+1]*Y.v[j*3+1]
               + (double)Y.v[i*3+2]*Y.v[j*3+2];
      kyy_acc += exp(2.0*d - 2.0);
    }
  float kyy = (float)(kyy_acc / 4096.0);

  kxy_kernel<<<NBATCH, 256, 0, stream>>>(X, Y, kxy);
  loss_kernel<<<1, 64, 0, stream>>>(kxx, kxy, kyy, out);
}

// Round 3
// 827.540 us; speedup vs baseline: 2.4406x; 2.4406x over previous
//
#include <hip/hip_runtime.h>
#include <cmath>

#define NNODES 32768
#define NEDGES 524288
#define NBATCH 16
#define NSAMP  2048
#define EPS    1e-5f

#define PK1 136   // 128 + 8 pad (bf16): ds_read_b128 conflict-free
#define PK2 80    // 64 + 16 pad: reads and b16 writes conflict-free

typedef short s16x8 __attribute__((ext_vector_type(8)));
typedef float f32x4 __attribute__((ext_vector_type(4)));
typedef unsigned short ushort_t;

struct YArr { float v[192]; };

static __device__ __forceinline__ unsigned short f2bf(float f) {
  unsigned int u = __float_as_uint(f);
  u = (u + 0x7fffu + ((u >> 16) & 1u)) >> 16;   // RN-even
  return (unsigned short)u;
}
static __device__ __forceinline__ float bf2f(unsigned short b) {
  return __uint_as_float(((unsigned int)b) << 16);
}

// ------------- weight prep: fp32 [K][64] -> bf16 hi/lo transposed [64][PK] ----
__global__ __launch_bounds__(256) void prep_weights_kernel(
    const float* __restrict__ m1W, const float* __restrict__ m2W,
    const float* __restrict__ u1W, const float* __restrict__ u2W,
    ushort_t* __restrict__ w1e_hi, ushort_t* __restrict__ w1e_lo,
    ushort_t* __restrict__ w2e_hi, ushort_t* __restrict__ w2e_lo,
    ushort_t* __restrict__ w1n_hi, ushort_t* __restrict__ w1n_lo,
    ushort_t* __restrict__ w2n_hi, ushort_t* __restrict__ w2n_lo)
{
  int t = blockIdx.x * 256 + threadIdx.x;
  if (t >= 2 * 4 * 12288) return;
  int net = t / 49152;            // 0 = edge(m), 1 = node(u)
  int r0  = t % 49152;
  int l   = r0 / 12288;
  int r   = r0 % 12288;
  float w; ushort_t *dh, *dl;
  if (r < 8192) {                 // W1 [128][64]
    int k = r >> 6, n = r & 63;
    w = (net ? u1W : m1W)[l*8192 + k*64 + n];
    int off = l*64*PK1 + n*PK1 + k;
    dh = (net ? w1n_hi : w1e_hi) + off;
    dl = (net ? w1n_lo : w1e_lo) + off;
  } else {                        // W2 [64][64]
    int r2 = r - 8192;
    int k = r2 >> 6, n = r2 & 63;
    w = (net ? u2W : m2W)[l*4096 + k*64 + n];
    int off = l*64*PK2 + n*PK2 + k;
    dh = (net ? w2n_hi : w2e_hi) + off;
    dl = (net ? w2n_lo : w2e_lo) + off;
  }
  unsigned short hb = f2bf(w);
  *dh = hb;
  *dl = f2bf(w - bf2f(hb));
}

// ------------- encoder -------------
__global__ __launch_bounds__(256) void encoder_kernel(
    const float* __restrict__ x, const float* __restrict__ W,
    const float* __restrict__ b, float* __restrict__ hf,
    ushort_t* __restrict__ hhi, ushort_t* __restrict__ hlo)
{
  int idx = blockIdx.x * 256 + threadIdx.x;   // n*64 + c
  int n = idx >> 6, c = idx & 63;
  float v = b[c];
  v = fmaf(x[n*3+0], W[0*64+c], v);
  v = fmaf(x[n*3+1], W[1*64+c], v);
  v = fmaf(x[n*3+2], W[2*64+c], v);
  hf[idx] = v;
  unsigned short hb = f2bf(v);
  hhi[idx] = hb;
  hlo[idx] = f2bf(v - bf2f(hb));
}

// ------------- CSR build (graph static across layers) -------------
__global__ __launch_bounds__(256) void count_kernel(const int* __restrict__ edst,
                                                    int* __restrict__ cnt) {
  int e = blockIdx.x * 256 + threadIdx.x;
  if (e < NEDGES) atomicAdd(&cnt[edst[e]], 1);
}

__global__ __launch_bounds__(1024) void scan_kernel(const int* __restrict__ cnt,
                                                    int* __restrict__ offs,
                                                    int* __restrict__ cursor) {
  __shared__ int sc[1024];
  int tid = threadIdx.x;
  int base = tid * 32;
  int s = 0;
  #pragma unroll
  for (int i = 0; i < 32; i++) s += cnt[base + i];
  sc[tid] = s; __syncthreads();
  int own = s;
  for (int off = 1; off < 1024; off <<= 1) {
    int v = (tid >= off) ? sc[tid - off] : 0;
    __syncthreads();
    sc[tid] += v;
    __syncthreads();
  }
  int run = sc[tid] - own;   // exclusive prefix of this chunk
  for (int i = 0; i < 32; i++) {
    offs[base + i] = run; cursor[base + i] = run;
    run += cnt[base + i];
  }
}

__global__ __launch_bounds__(256) void fill_kernel(
    const int* __restrict__ esrc, const int* __restrict__ edst,
    int* __restrict__ cursor, int* __restrict__ psrc, int* __restrict__ pdst) {
  int e = blockIdx.x * 256 + threadIdx.x;
  if (e < NEDGES) {
    int d = edst[e];
    int pos = atomicAdd(&cursor[d], 1);
    psrc[pos] = esrc[e];
    pdst[pos] = d;
  }
}

// ------------- MFMA two-layer MLP, full hi/lo x hi/lo (4 products) -----
// Wave handles 32 rows. Edge variant: rows = CSR-ordered edges, writes m2buf
// (contiguous, no atomics). Node variant: rows = nodes, writes u.
template<int IS_EDGE>
__global__ __launch_bounds__(256, 2) void mlp2_mfma_kernel(
    const ushort_t* __restrict__ Ahi, const ushort_t* __restrict__ Alo,
    const float* __restrict__ aggF,
    const int* __restrict__ psrc, const int* __restrict__ pdst,
    const ushort_t* __restrict__ W1hi, const ushort_t* __restrict__ W1lo,
    const float* __restrict__ b1,
    const ushort_t* __restrict__ W2hi, const ushort_t* __restrict__ W2lo,
    const float* __restrict__ b2,
    float* __restrict__ out, int M)
{
  __shared__ ushort_t sW1hi[64*PK1];
  __shared__ ushort_t sW1lo[64*PK1];
  __shared__ ushort_t sMh[4][32*PK2];
  __shared__ ushort_t sMl[4][32*PK2];

  int tid = threadIdx.x;
  {
    const uint4* g1 = (const uint4*)W1hi; uint4* s1 = (uint4*)sW1hi;
    const uint4* g2 = (const uint4*)W1lo; uint4* s2 = (uint4*)sW1lo;
    for (int i = tid; i < 64*PK1/8; i += 256) { s1[i] = g1[i]; s2[i] = g2[i]; }
  }
  int lane = tid & 63, wave = tid >> 6;
  int l15 = lane & 15, quad = lane >> 4;

  // resident W2 fragments (hi+lo)
  s16x8 w2h[2][4], w2l[2][4];
  #pragma unroll
  for (int kb = 0; kb < 2; kb++)
    #pragma unroll
    for (int ct = 0; ct < 4; ct++) {
      int off = (ct*16 + l15)*PK2 + kb*32 + quad*8;
      w2h[kb][ct] = *(const s16x8*)(W2hi + off);
      w2l[kb][ct] = *(const s16x8*)(W2lo + off);
    }
  float b1v[4], b2v[4];
  #pragma unroll
  for (int ct = 0; ct < 4; ct++) { b1v[ct] = b1[ct*16+l15]; b2v[ct] = b2[ct*16+l15]; }
  __syncthreads();

  ushort_t* myMh = sMh[wave];
  ushort_t* myMl = sMl[wave];

  for (int base = blockIdx.x * 128; base < M; base += gridDim.x * 128) {
    int e0 = base + wave * 32;

    // ---- gather A fragments (hi/lo) ----
    s16x8 ah[2][4], al[2][4];
    #pragma unroll
    for (int rt = 0; rt < 2; rt++) {
      int em = e0 + rt*16 + l15;          // A-layout row = lane&15
      if (IS_EDGE) {
        int nd = pdst[em], ns = psrc[em]; // xi = h[dst] (k<64), xj = h[src]
        #pragma unroll
        for (int kb = 0; kb < 4; kb++) {
          int node = (kb < 2) ? nd : ns;
          int off = node*64 + (kb & 1)*32 + quad*8;
          ah[rt][kb] = *(const s16x8*)(Ahi + off);
          al[rt][kb] = *(const s16x8*)(Alo + off);
        }
      } else {
        #pragma unroll
        for (int kb = 0; kb < 2; kb++) {  // h part
          int off = em*64 + kb*32 + quad*8;
          ah[rt][kb] = *(const s16x8*)(Ahi + off);
          al[rt][kb] = *(const s16x8*)(Alo + off);
        }
        #pragma unroll
        for (int kb = 2; kb < 4; kb++) {  // agg part: fp32 -> split in-reg
          int off = em*64 + (kb & 1)*32 + quad*8;
          float4 v0 = *(const float4*)(aggF + off);
          float4 v1 = *(const float4*)(aggF + off + 4);
          float vv[8] = {v0.x,v0.y,v0.z,v0.w,v1.x,v1.y,v1.z,v1.w};
          s16x8 hh, ll;
          #pragma unroll
          for (int j = 0; j < 8; j++) {
            unsigned short hb = f2bf(vv[j]);
            hh[j] = (short)hb;
            ll[j] = (short)f2bf(vv[j] - bf2f(hb));
          }
          ah[rt][kb] = hh; al[rt][kb] = ll;
        }
      }
    }

    // ---- layer 1: 4-product compensated bf16 (ll, lh, hl, hh) ----
    f32x4 acc[2][4];
    #pragma unroll
    for (int rt = 0; rt < 2; rt++)
      #pragma unroll
      for (int ct = 0; ct < 4; ct++)
        acc[rt][ct] = (f32x4){0.f, 0.f, 0.f, 0.f};

    #pragma unroll
    for (int kb = 0; kb < 4; kb++) {
      #pragma unroll
      for (int ct = 0; ct < 4; ct++) {
        int woff = (ct*16 + l15)*PK1 + kb*32 + quad*8;
        s16x8 bh = *(const s16x8*)&sW1hi[woff];
        s16x8 bl = *(const s16x8*)&sW1lo[woff];
        #pragma unroll
        for (int rt = 0; rt < 2; rt++) {
          acc[rt][ct] = __builtin_amdgcn_mfma_f32_16x16x32_bf16(al[rt][kb], bl, acc[rt][ct], 0, 0, 0);
          acc[rt][ct] = __builtin_amdgcn_mfma_f32_16x16x32_bf16(al[rt][kb], bh, acc[rt][ct], 0, 0, 0);
          acc[rt][ct] = __builtin_amdgcn_mfma_f32_16x16x32_bf16(ah[rt][kb], bl, acc[rt][ct], 0, 0, 0);
          acc[rt][ct] = __builtin_amdgcn_mfma_f32_16x16x32_bf16(ah[rt][kb], bh, acc[rt][ct], 0, 0, 0);
        }
      }
    }

    // ---- m1: bias+relu in fp32, split hi/lo -> LDS ----
    #pragma unroll
    for (int rt = 0; rt < 2; rt++)
      #pragma unroll
      for (int ct = 0; ct < 4; ct++)
        #pragma unroll
        for (int r = 0; r < 4; r++) {
          float v = fmaxf(acc[rt][ct][r] + b1v[ct], 0.f);
          unsigned short hb = f2bf(v);
          int idx = (rt*16 + quad*4 + r)*PK2 + ct*16 + l15;
          myMh[idx] = hb;
          myMl[idx] = f2bf(v - bf2f(hb));
        }

    // ---- layer 2: 4-product compensated ----
    f32x4 facc[2][4];
    #pragma unroll
    for (int rt = 0; rt < 2; rt++)
      #pragma unroll
      for (int ct = 0; ct < 4; ct++)
        facc[rt][ct] = (f32x4){0.f, 0.f, 0.f, 0.f};

    #pragma unroll
    for (int kb = 0; kb < 2; kb++) {
      s16x8 mh[2], ml[2];
      #pragma unroll
      for (int rt = 0; rt < 2; rt++) {
        int idx = (rt*16 + l15)*PK2 + kb*32 + quad*8;
        mh[rt] = *(const s16x8*)&myMh[idx];
        ml[rt] = *(const s16x8*)&myMl[idx];
      }
      #pragma unroll
      for (int ct = 0; ct < 4; ct++)
        #pragma unroll
        for (int rt = 0; rt < 2; rt++) {
          facc[rt][ct] = __builtin_amdgcn_mfma_f32_16x16x32_bf16(ml[rt], w2l[kb][ct], facc[rt][ct], 0, 0, 0);
          facc[rt][ct] = __builtin_amdgcn_mfma_f32_16x16x32_bf16(ml[rt], w2h[kb][ct], facc[rt][ct], 0, 0, 0);
          facc[rt][ct] = __builtin_amdgcn_mfma_f32_16x16x32_bf16(mh[rt], w2l[kb][ct], facc[rt][ct], 0, 0, 0);
          facc[rt][ct] = __builtin_amdgcn_mfma_f32_16x16x32_bf16(mh[rt], w2h[kb][ct], facc[rt][ct], 0, 0, 0);
        }
    }

    // ---- epilogue: bias+relu, contiguous store (CSR order / node order) ----
    #pragma unroll
    for (int rt = 0; rt < 2; rt++)
      #pragma unroll
      for (int r = 0; r < 4; r++) {
        int grow = e0 + rt*16 + quad*4 + r;
        #pragma unroll
        for (int ct = 0; ct < 4; ct++) {
          float v = fmaxf(facc[rt][ct][r] + b2v[ct], 0.f);
          out[(size_t)grow*64 + ct*16 + l15] = v;
        }
      }
  }
}

// ------------- aggregate CSR-ordered messages: agg[n] = sum m2[seg(n)] ----
__global__ __launch_bounds__(256) void agg_kernel(
    const float* __restrict__ m2buf, const int* __restrict__ offs,
    const int* __restrict__ cnt, float* __restrict__ agg)
{
  int t = blockIdx.x * 256 + threadIdx.x;
  int n = t >> 4;
  int c4 = (t & 15) * 4;
  int s = offs[n], e = s + cnt[n];
  float4 a = {0.f, 0.f, 0.f, 0.f};
  for (int i = s; i < e; i++) {
    float4 v = *(const float4*)(m2buf + (size_t)i*64 + c4);
    a.x += v.x; a.y += v.y; a.z += v.z; a.w += v.w;
  }
  *(float4*)(agg + (size_t)n*64 + c4) = a;
}

// ------------- InstanceNorm, 3 phases -------------
__global__ __launch_bounds__(1024) void in_partial_kernel(
    const float* __restrict__ u, float* __restrict__ pA, float* __restrict__ pB)
{
  int g = blockIdx.x >> 3, sb = blockIdx.x & 7;
  int c = threadIdx.x & 63, rg = threadIdx.x >> 6;
  const float* ub = u + ((size_t)g * NSAMP + sb * 256) * 64;
  float s = 0.f, s2 = 0.f;
  for (int i = rg; i < 256; i += 16) {
    float v = ub[i*64 + c];
    s += v; s2 += v*v;
  }
  __shared__ float ps[16][64], ps2[16][64];
  ps[rg][c] = s; ps2[rg][c] = s2;
  __syncthreads();
  if (rg == 0) {
    float a = 0.f, b = 0.f;
    #pragma unroll
    for (int j = 0; j < 16; j++) { a += ps[j][c]; b += ps2[j][c]; }
    pA[(g*8+sb)*64 + c] = a;
    pB[(g*8+sb)*64 + c] = b;
  }
}

__global__ __launch_bounds__(64) void in_finalize_kernel(
    const float* __restrict__ pA, const float* __restrict__ pB,
    float* __restrict__ mean, float* __restrict__ rstd)
{
  int g = blockIdx.x, c = threadIdx.x;
  float a = 0.f, b = 0.f;
  for (int j = 0; j < 8; j++) { a += pA[(g*8+j)*64 + c]; b += pB[(g*8+j)*64 + c]; }
  float m = a * (1.f / NSAMP);
  float var = b * (1.f / NSAMP) - m * m;
  mean[g*64 + c] = m;
  rstd[g*64 + c] = rsqrtf(var + EPS);
}

__global__ __launch_bounds__(256) void in_apply_kernel(
    const float* __restrict__ u, const float* __restrict__ mean,
    const float* __restrict__ rstd, float* __restrict__ hf,
    ushort_t* __restrict__ hhi, ushort_t* __restrict__ hlo)
{
  int idx = blockIdx.x * 256 + threadIdx.x;   // n*64 + c
  int c = idx & 63, g = idx >> 17;
  float v = (u[idx] - mean[g*64 + c]) * rstd[g*64 + c];
  hf[idx] = v;
  unsigned short hb = f2bf(v);
  hhi[idx] = hb;
  hlo[idx] = f2bf(v - bf2f(hb));
}

// ------------- decoder + unit normalize -------------
__global__ __launch_bounds__(64) void decoder_kernel(
    const float* __restrict__ h, const float* __restrict__ W,
    const float* __restrict__ b, float* __restrict__ X)
{
  __shared__ float sh[64][65];
  int lane = threadIdx.x;
  int nb = blockIdx.x * 64;
  for (int r = 0; r < 64; r++) sh[r][lane] = h[(size_t)(nb + r) * 64 + lane];
  __syncthreads();
  float a0 = b[0], a1 = b[1], a2 = b[2];
  #pragma unroll
  for (int c = 0; c < 64; c++) {
    float v = sh[lane][c];
    a0 = fmaf(v, W[c*3+0], a0);
    a1 = fmaf(v, W[c*3+1], a1);
    a2 = fmaf(v, W[c*3+2], a2);
  }
  float inv = 1.f / sqrtf(a0*a0 + a1*a1 + a2*a2);
  int n = nb + lane;
  X[n*3+0] = a0 * inv;
  X[n*3+1] = a1 * inv;
  X[n*3+2] = a2 * inv;
}

// ------------- MMD -------------
__device__ inline float block_reduce_sum(float v) {
  #pragma unroll
  for (int o = 32; o > 0; o >>= 1) v += __shfl_down(v, o, 64);
  __shared__ float red[4];
  int lane = threadIdx.x & 63, w = threadIdx.x >> 6;
  if (lane == 0) red[w] = v;
  __syncthreads();
  float t = 0.f;
  if (threadIdx.x == 0) t = red[0] + red[1] + red[2] + red[3];
  return t;
}

__global__ __launch_bounds__(256) void kxx_kernel(
    const float* __restrict__ X, float* __restrict__ kxx)
{
  int b  = blockIdx.x >> 5;
  int nt = blockIdx.x & 31;
  const float* Xb = X + (size_t)b * NSAMP * 3;
  __shared__ float sx[192];
  if (threadIdx.x < 192) sx[threadIdx.x] = Xb[nt*192 + threadIdx.x];
  __syncthreads();
  float ps = 0.f;
  for (int it = 0; it < 8; it++) {
    int m = it*256 + threadIdx.x;
    float x0 = Xb[m*3+0], x1 = Xb[m*3+1], x2 = Xb[m*3+2];
    #pragma unroll
    for (int n = 0; n < 64; n++) {
      float d = x0*sx[n*3+0] + x1*sx[n*3+1] + x2*sx[n*3+2];
      ps += __expf(2.f*d - 2.f);
    }
  }
  float t = block_reduce_sum(ps);
  if (threadIdx.x == 0) atomicAdd(&kxx[b], t);
}

__global__ __launch_bounds__(256) void kxy_kernel(
    const float* __restrict__ X, YArr Y, float* __restrict__ kxy)
{
  int b = blockIdx.x;
  const float* Xb = X + (size_t)b * NSAMP * 3;
  float ps = 0.f;
  for (int it = 0; it < 8; it++) {
    int n = it*256 + threadIdx.x;
    float x0 = Xb[n*3+0], x1 = Xb[n*3+1], x2 = Xb[n*3+2];
    #pragma unroll
    for (int m = 0; m < 64; m++) {
      float d = x0*Y.v[m*3+0] + x1*Y.v[m*3+1] + x2*Y.v[m*3+2];
      ps += __expf(2.f*d - 2.f);
    }
  }
  float t = block_reduce_sum(ps);
  if (threadIdx.x == 0) kxy[b] = t;
}

__global__ void loss_kernel(const float* __restrict__ kxx,
                            const float* __restrict__ kxy,
                            float kyy, float* __restrict__ out)
{
  if (threadIdx.x == 0 && blockIdx.x == 0) {
    float s = 0.f;
    for (int b = 0; b < NBATCH; b++)
      s += kxx[b] * (1.0f/((float)NSAMP*(float)NSAMP))
         - 2.0f * kxy[b] * (1.0f/((float)NSAMP*64.0f));
    out[0] = s * (1.0f/NBATCH) + kyy;
  }
}

// ------------- launch -------------
extern "C" void kernel_launch(void* const* d_in, const int* in_sizes, int n_in,
                              void* d_out, int out_size, void* d_ws, size_t ws_size,
                              hipStream_t stream)
{
  const float* x    = (const float*)d_in[0];
  const int*   esrc = (const int*)  d_in[1];
  const int*   edst = (const int*)  d_in[2];
  const float* encW = (const float*)d_in[4];
  const float* encb = (const float*)d_in[5];
  const float* m1W  = (const float*)d_in[6];
  const float* m1b  = (const float*)d_in[7];
  const float* m2W  = (const float*)d_in[8];
  const float* m2b  = (const float*)d_in[9];
  const float* u1W  = (const float*)d_in[10];
  const float* u1b  = (const float*)d_in[11];
  const float* u2W  = (const float*)d_in[12];
  const float* u2b  = (const float*)d_in[13];
  const float* decW = (const float*)d_in[14];
  const float* decb = (const float*)d_in[15];
  float* out = (float*)d_out;

  const size_t NF = (size_t)NNODES * 64;
  float* h_f   = (float*)d_ws;
  float* agg   = h_f + NF;
  float* u_buf = agg + NF;
  float* m2buf = u_buf + NF;                      // [E,64] fp32, 134 MB
  float* kxx   = m2buf + (size_t)NEDGES * 64;
  float* kxy   = kxx + 16;
  float* pA    = kxy + 16;                        // [16*8*64]
  float* pB    = pA + 16*8*64;
  float* meanb = pB + 16*8*64;                    // [16*64]
  float* rstdb = meanb + 16*64;
  int* icnt    = (int*)(rstdb + 16*64);           // [32768]
  int* ioffs   = icnt + NNODES;
  int* icur    = ioffs + NNODES;
  int* psrc    = icur + NNODES;                   // [E]
  int* pdst    = psrc + NEDGES;
  ushort_t* us = (ushort_t*)(pdst + NEDGES);
  ushort_t* h_hi = us;          us += NF;
  ushort_t* h_lo = us;          us += NF;
  ushort_t* w1e_hi = us;        us += 4*64*PK1;
  ushort_t* w1e_lo = us;        us += 4*64*PK1;
  ushort_t* w2e_hi = us;        us += 4*64*PK2;
  ushort_t* w2e_lo = us;        us += 4*64*PK2;
  ushort_t* w1n_hi = us;        us += 4*64*PK1;
  ushort_t* w1n_lo = us;        us += 4*64*PK1;
  ushort_t* w2n_hi = us;        us += 4*64*PK2;
  ushort_t* w2n_lo = us;        us += 4*64*PK2;

  float* X = out + 1;

  prep_weights_kernel<<<384, 256, 0, stream>>>(
      m1W, m2W, u1W, u2W,
      w1e_hi, w1e_lo, w2e_hi, w2e_lo, w1n_hi, w1n_lo, w2n_hi, w2n_lo);

  encoder_kernel<<<NNODES*64/256, 256, 0, stream>>>(x, encW, encb, h_f, h_hi, h_lo);

  // CSR build (once; graph static across layers)
  hipMemsetAsync(icnt, 0, NNODES * sizeof(int), stream);
  count_kernel<<<NEDGES/256, 256, 0, stream>>>(edst, icnt);
  scan_kernel<<<1, 1024, 0, stream>>>(icnt, ioffs, icur);
  fill_kernel<<<NEDGES/256, 256, 0, stream>>>(esrc, edst, icur, psrc, pdst);

  for (int l = 0; l < 4; l++) {
    mlp2_mfma_kernel<1><<<512, 256, 0, stream>>>(
        h_hi, h_lo, nullptr, psrc, pdst,
        w1e_hi + (size_t)l*64*PK1, w1e_lo + (size_t)l*64*PK1, m1b + l*64,
        w2e_hi + (size_t)l*64*PK2, w2e_lo + (size_t)l*64*PK2, m2b + l*64,
        m2buf, NEDGES);
    agg_kernel<<<NNODES*16/256, 256, 0, stream>>>(m2buf, ioffs, icnt, agg);
    mlp2_mfma_kernel<0><<<256, 256, 0, stream>>>(
        h_hi, h_lo, agg, nullptr, nullptr,
        w1n_hi + (size_t)l*64*PK1, w1n_lo + (size_t)l*64*PK1, u1b + l*64,
        w2n_hi + (size_t)l*64*PK2, w2n_lo + (size_t)l*64*PK2, u2b + l*64,
        u_buf, NNODES);
    in_partial_kernel<<<NBATCH*8, 1024, 0, stream>>>(u_buf, pA, pB);
    in_finalize_kernel<<<NBATCH, 64, 0, stream>>>(pA, pB, meanb, rstdb);
    in_apply_kernel<<<NNODES*64/256, 256, 0, stream>>>(u_buf, meanb, rstdb, h_f, h_hi, h_lo);
  }

  decoder_kernel<<<NNODES/64, 64, 0, stream>>>(h_f, decW, decb, X);

  hipMemsetAsync(kxx, 0, 16 * sizeof(float), stream);
  kxx_kernel<<<NBATCH*32, 256, 0, stream>>>(X, kxx);

  YArr Y;
  {
    const double pi = 3.14159265358979323846;
    double phi = pi * (3.0 - sqrt(5.0));
    for (int i = 0; i < 64; i++) {
      double y  = 1.0 - 2.0 * (double)i / 63.0;
      double r  = sqrt(fmax(0.0, 1.0 - y*y));
      double th = phi * (double)i;
      Y.v[i*3+0] = (float)(cos(th) * r);
      Y.v[i*3+1] = (float)y;
      Y.v[i*3+2] = (float)(sin(th) * r);
    }
  }
  double kyy_acc = 0.0;
  for (int i = 0; i < 64; i++)
    for (int j = 0; j < 64; j++) {
      double d = (double)Y.v[i*3+0]*Y.v[j*3+0]
               + (double)Y.v[i*3+1]*Y.v[j*3+1]
               + (double)Y.v[i*3+2]*Y.v[j*3+2];
      kyy_acc += exp(2.0*d - 2.0);
    }
  float kyy = (float)(kyy_acc / 4096.0);

  kxy_kernel<<<NBATCH, 256, 0, stream>>>(X, Y, kxy);
  loss_kernel<<<1, 64, 0, stream>>>(kxx, kxy, kyy, out);
}

// Round 4
// 518.051 us; speedup vs baseline: 3.8986x; 1.5974x over previous
//
#include <hip/hip_runtime.h>
#include <cmath>

#define NNODES 32768
#define NEDGES 524288
#define NBATCH 16
#define NSAMP  2048
#define EPS    1e-5f

#define PK1 136   // K=128 + 8 pad (bf16)
#define PK2 72    // K=64 + 8 pad

typedef short s16x8 __attribute__((ext_vector_type(8)));
typedef float f32x4 __attribute__((ext_vector_type(4)));
typedef unsigned short ushort_t;

struct YArr { float v[192]; };

static __device__ __forceinline__ unsigned short f2bf(float f) {
  unsigned int u = __float_as_uint(f);
  u = (u + 0x7fffu + ((u >> 16) & 1u)) >> 16;   // RN-even
  return (unsigned short)u;
}
static __device__ __forceinline__ float bf2f(unsigned short b) {
  return __uint_as_float(((unsigned int)b) << 16);
}

// ------------- weight prep -------------
// edge Wc (P|Q combined): [l][j=0..127][PK2] hi/lo, j<64 -> P cols, j>=64 -> Q cols
// edge W2: [l][j][PK2];  node W1: [l][j][PK1];  node W2: [l][j][PK2]
__global__ __launch_bounds__(256) void prep_weights_kernel(
    const float* __restrict__ m1W, const float* __restrict__ m2W,
    const float* __restrict__ u1W, const float* __restrict__ u2W,
    ushort_t* __restrict__ wce_hi, ushort_t* __restrict__ wce_lo,
    ushort_t* __restrict__ w2e_hi, ushort_t* __restrict__ w2e_lo,
    ushort_t* __restrict__ w1n_hi, ushort_t* __restrict__ w1n_lo,
    ushort_t* __restrict__ w2n_hi, ushort_t* __restrict__ w2n_lo)
{
  int t = blockIdx.x * 256 + threadIdx.x;
  if (t >= 4 * 24576) return;
  int l = t / 24576;
  int r = t % 24576;
  float w; ushort_t *dh, *dl;
  if (r < 8192) {                       // Wc: j = out (0..127), k = in-node channel (0..63)
    int j = r >> 6, k = r & 63;
    // P part: m1 = concat(xi, xj) @ m1W ; xi rows 0..63, xj rows 64..127
    w = (j < 64) ? m1W[l*8192 + k*64 + j] : m1W[l*8192 + (64 + k)*64 + (j - 64)];
    int off = l*128*PK2 + j*PK2 + k;
    dh = wce_hi + off; dl = wce_lo + off;
  } else if (r < 12288) {               // W2 edge [64][64]
    int r2 = r - 8192;
    int k = r2 >> 6, j = r2 & 63;
    w = m2W[l*4096 + k*64 + j];
    int off = l*64*PK2 + j*PK2 + k;
    dh = w2e_hi + off; dl = w2e_lo + off;
  } else if (r < 20480) {               // W1 node [128][64]
    int r3 = r - 12288;
    int k = r3 >> 6, j = r3 & 63;
    w = u1W[l*8192 + k*64 + j];
    int off = l*64*PK1 + j*PK1 + k;
    dh = w1n_hi + off; dl = w1n_lo + off;
  } else {                              // W2 node [64][64]
    int r4 = r - 20480;
    int k = r4 >> 6, j = r4 & 63;
    w = u2W[l*4096 + k*64 + j];
    int off = l*64*PK2 + j*PK2 + k;
    dh = w2n_hi + off; dl = w2n_lo + off;
  }
  unsigned short hb = f2bf(w);
  *dh = hb;
  *dl = f2bf(w - bf2f(hb));
}

// ------------- encoder -------------
__global__ __launch_bounds__(256) void encoder_kernel(
    const float* __restrict__ x, const float* __restrict__ W,
    const float* __restrict__ b, float* __restrict__ hf,
    ushort_t* __restrict__ hhi, ushort_t* __restrict__ hlo)
{
  int idx = blockIdx.x * 256 + threadIdx.x;   // n*64 + c
  int n = idx >> 6, c = idx & 63;
  float v = b[c];
  v = fmaf(x[n*3+0], W[0*64+c], v);
  v = fmaf(x[n*3+1], W[1*64+c], v);
  v = fmaf(x[n*3+2], W[2*64+c], v);
  hf[idx] = v;
  unsigned short hb = f2bf(v);
  hhi[idx] = hb;
  hlo[idx] = f2bf(v - bf2f(hb));
}

// ------------- CSR build -------------
__global__ __launch_bounds__(256) void count_kernel(const int* __restrict__ edst,
                                                    int* __restrict__ cnt) {
  int e = blockIdx.x * 256 + threadIdx.x;
  if (e < NEDGES) atomicAdd(&cnt[edst[e]], 1);
}

__global__ __launch_bounds__(1024) void scan_kernel(const int* __restrict__ cnt,
                                                    int* __restrict__ offs,
                                                    int* __restrict__ cursor) {
  __shared__ int sc[1024];
  int tid = threadIdx.x;
  int base = tid * 32;
  int s = 0;
  #pragma unroll
  for (int i = 0; i < 32; i++) s += cnt[base + i];
  sc[tid] = s; __syncthreads();
  int own = s;
  for (int off = 1; off < 1024; off <<= 1) {
    int v = (tid >= off) ? sc[tid - off] : 0;
    __syncthreads();
    sc[tid] += v;
    __syncthreads();
  }
  int run = sc[tid] - own;
  for (int i = 0; i < 32; i++) {
    offs[base + i] = run; cursor[base + i] = run;
    run += cnt[base + i];
  }
}

__global__ __launch_bounds__(256) void fill_kernel(
    const int* __restrict__ esrc, const int* __restrict__ edst,
    int* __restrict__ cursor, int* __restrict__ psrc, int* __restrict__ pdst) {
  int e = blockIdx.x * 256 + threadIdx.x;
  if (e < NEDGES) {
    int d = edst[e];
    int pos = atomicAdd(&cursor[d], 1);
    psrc[pos] = esrc[e];
    pdst[pos] = d;
  }
}

// ------------- PQ precompute: [N,64] @ [64,128] -> Pbuf, Qbuf (fp32) -----
__global__ __launch_bounds__(256, 4) void pq_kernel(
    const ushort_t* __restrict__ Ahi, const ushort_t* __restrict__ Alo,
    const ushort_t* __restrict__ Wh, const ushort_t* __restrict__ Wl,
    float* __restrict__ Pbuf, float* __restrict__ Qbuf)
{
  __shared__ ushort_t sWh[128*PK2];
  __shared__ ushort_t sWl[128*PK2];
  int tid = threadIdx.x;
  {
    const uint4* g1 = (const uint4*)Wh; uint4* s1 = (uint4*)sWh;
    const uint4* g2 = (const uint4*)Wl; uint4* s2 = (uint4*)sWl;
    for (int i = tid; i < 128*PK2/8; i += 256) { s1[i] = g1[i]; s2[i] = g2[i]; }
  }
  int lane = tid & 63, wave = tid >> 6;
  int l15 = lane & 15, quad = lane >> 4;
  __syncthreads();

  int base = blockIdx.x * 128 + wave * 32;

  s16x8 ah[2][2], al[2][2];
  #pragma unroll
  for (int rt = 0; rt < 2; rt++) {
    int em = base + rt*16 + l15;
    #pragma unroll
    for (int kb = 0; kb < 2; kb++) {
      int off = em*64 + kb*32 + quad*8;
      ah[rt][kb] = *(const s16x8*)(Ahi + off);
      al[rt][kb] = *(const s16x8*)(Alo + off);
    }
  }

  f32x4 acc[2][8];
  #pragma unroll
  for (int rt = 0; rt < 2; rt++)
    #pragma unroll
    for (int ct = 0; ct < 8; ct++)
      acc[rt][ct] = (f32x4){0.f, 0.f, 0.f, 0.f};

  #pragma unroll
  for (int kb = 0; kb < 2; kb++)
    #pragma unroll
    for (int ct = 0; ct < 8; ct++) {
      int woff = (ct*16 + l15)*PK2 + kb*32 + quad*8;
      s16x8 bh = *(const s16x8*)&sWh[woff];
      s16x8 bl = *(const s16x8*)&sWl[woff];
      #pragma unroll
      for (int rt = 0; rt < 2; rt++) {
        acc[rt][ct] = __builtin_amdgcn_mfma_f32_16x16x32_bf16(al[rt][kb], bl, acc[rt][ct], 0, 0, 0);
        acc[rt][ct] = __builtin_amdgcn_mfma_f32_16x16x32_bf16(al[rt][kb], bh, acc[rt][ct], 0, 0, 0);
        acc[rt][ct] = __builtin_amdgcn_mfma_f32_16x16x32_bf16(ah[rt][kb], bl, acc[rt][ct], 0, 0, 0);
        acc[rt][ct] = __builtin_amdgcn_mfma_f32_16x16x32_bf16(ah[rt][kb], bh, acc[rt][ct], 0, 0, 0);
      }
    }

  #pragma unroll
  for (int rt = 0; rt < 2; rt++)
    #pragma unroll
    for (int r = 0; r < 4; r++) {
      int row = base + rt*16 + quad*4 + r;
      #pragma unroll
      for (int ct = 0; ct < 8; ct++) {
        int j = ct*16 + l15;
        float v = acc[rt][ct][r];
        if (ct < 4) Pbuf[row*64 + j] = v;
        else        Qbuf[row*64 + (j - 64)] = v;
      }
    }
}

// ------------- fused edge MLP + segment-reduce -------------
// Wave handles 32 CSR-sorted edges: m1 = relu(P[dst]+Q[src]+b1) (fp32, lane=ch),
// hi/lo split -> LDS -> W2 MFMA (4-product) -> LDS -> run-length reduce by dst
// -> atomicAdd into agg. No m2 materialization.
__global__ __launch_bounds__(256, 3) void edge_fused_kernel(
    const float* __restrict__ Pbuf, const float* __restrict__ Qbuf,
    const int* __restrict__ psrc, const int* __restrict__ pdst,
    const float* __restrict__ b1,
    const ushort_t* __restrict__ W2hi, const ushort_t* __restrict__ W2lo,
    const float* __restrict__ b2,
    float* __restrict__ agg)
{
  __shared__ char smem[4][9216];   // per-wave: mh[32][72]+ml[32][72] (bf16)  OR  m2[32][68] (f32)
  __shared__ int  sSD[4][64];      // [0:32) src, [32:64) dst

  int tid = threadIdx.x;
  int lane = tid & 63, wave = tid >> 6;
  int l15 = lane & 15, quad = lane >> 4;

  ushort_t* mh = (ushort_t*)smem[wave];
  ushort_t* ml = mh + 32*PK2;
  float*    m2 = (float*)smem[wave];

  // resident W2 fragments (hi+lo)
  s16x8 w2h[2][4], w2l[2][4];
  #pragma unroll
  for (int kb = 0; kb < 2; kb++)
    #pragma unroll
    for (int ct = 0; ct < 4; ct++) {
      int off = (ct*16 + l15)*PK2 + kb*32 + quad*8;
      w2h[kb][ct] = *(const s16x8*)(W2hi + off);
      w2l[kb][ct] = *(const s16x8*)(W2lo + off);
    }
  float b1v = b1[lane];
  float b2v[4];
  #pragma unroll
  for (int ct = 0; ct < 4; ct++) b2v[ct] = b2[ct*16 + l15];

  for (int base = blockIdx.x * 128; base < NEDGES; base += gridDim.x * 128) {
    int e0 = base + wave * 32;

    // stage src/dst for this 32-edge window (wave-private)
    {
      const int* tb = (lane < 32) ? psrc : pdst;
      int i = (lane < 32) ? (e0 + lane) : (e0 + lane - 32);
      sSD[wave][lane] = tb[i];
    }

    // phase 1: m1 = relu(P[dst] + Q[src] + b1), lane = channel; hi/lo -> LDS
    #pragma unroll
    for (int rb = 0; rb < 4; rb++) {
      float pv[8], qv[8];
      #pragma unroll
      for (int i = 0; i < 8; i++) {
        int r = rb*8 + i;
        int s = sSD[wave][r];
        int d = sSD[wave][32 + r];
        qv[i] = Qbuf[(s << 6) + lane];
        pv[i] = Pbuf[(d << 6) + lane];
      }
      #pragma unroll
      for (int i = 0; i < 8; i++) {
        int r = rb*8 + i;
        float v = fmaxf(pv[i] + qv[i] + b1v, 0.f);
        unsigned short hb = f2bf(v);
        mh[r*PK2 + lane] = hb;
        ml[r*PK2 + lane] = f2bf(v - bf2f(hb));
      }
    }

    // phase 2: m2 = m1 @ W2 (4-product compensated)
    f32x4 facc[2][4];
    #pragma unroll
    for (int rt = 0; rt < 2; rt++)
      #pragma unroll
      for (int ct = 0; ct < 4; ct++)
        facc[rt][ct] = (f32x4){0.f, 0.f, 0.f, 0.f};

    #pragma unroll
    for (int kb = 0; kb < 2; kb++) {
      s16x8 mhf[2], mlf[2];
      #pragma unroll
      for (int rt = 0; rt < 2; rt++) {
        int idx = (rt*16 + l15)*PK2 + kb*32 + quad*8;
        mhf[rt] = *(const s16x8*)&mh[idx];
        mlf[rt] = *(const s16x8*)&ml[idx];
      }
      #pragma unroll
      for (int ct = 0; ct < 4; ct++)
        #pragma unroll
        for (int rt = 0; rt < 2; rt++) {
          facc[rt][ct] = __builtin_amdgcn_mfma_f32_16x16x32_bf16(mlf[rt], w2l[kb][ct], facc[rt][ct], 0, 0, 0);
          facc[rt][ct] = __builtin_amdgcn_mfma_f32_16x16x32_bf16(mlf[rt], w2h[kb][ct], facc[rt][ct], 0, 0, 0);
          facc[rt][ct] = __builtin_amdgcn_mfma_f32_16x16x32_bf16(mhf[rt], w2l[kb][ct], facc[rt][ct], 0, 0, 0);
          facc[rt][ct] = __builtin_amdgcn_mfma_f32_16x16x32_bf16(mhf[rt], w2h[kb][ct], facc[rt][ct], 0, 0, 0);
        }
    }

    // phase 3: m2 -> LDS (C-layout rows), overlaps mh/ml (values depend on their reads)
    #pragma unroll
    for (int rt = 0; rt < 2; rt++)
      #pragma unroll
      for (int ct = 0; ct < 4; ct++)
        #pragma unroll
        for (int r = 0; r < 4; r++)
          m2[(rt*16 + quad*4 + r)*68 + ct*16 + l15] = fmaxf(facc[rt][ct][r] + b2v[ct], 0.f);

    // phase 4: run-length segment reduce by dst (dst is sorted), lane = channel
    int curd = sSD[wave][32];
    float acc = 0.f;
    #pragma unroll
    for (int r = 0; r < 32; r++) {
      int d = sSD[wave][32 + r];          // wave-uniform
      float v = m2[r*68 + lane];
      if (d != curd) {
        unsafeAtomicAdd(&agg[(curd << 6) + lane], acc);
        acc = 0.f; curd = d;
      }
      acc += v;
    }
    unsafeAtomicAdd(&agg[(curd << 6) + lane], acc);
  }
}

// ------------- node two-layer MLP (MFMA, 4-product) -------------
__global__ __launch_bounds__(256, 2) void node_mfma_kernel(
    const ushort_t* __restrict__ Ahi, const ushort_t* __restrict__ Alo,
    const float* __restrict__ aggF,
    const ushort_t* __restrict__ W1hi, const ushort_t* __restrict__ W1lo,
    const float* __restrict__ b1,
    const ushort_t* __restrict__ W2hi, const ushort_t* __restrict__ W2lo,
    const float* __restrict__ b2,
    float* __restrict__ out)
{
  __shared__ ushort_t sW1hi[64*PK1];
  __shared__ ushort_t sW1lo[64*PK1];
  __shared__ ushort_t sMh[4][32*PK2];
  __shared__ ushort_t sMl[4][32*PK2];

  int tid = threadIdx.x;
  {
    const uint4* g1 = (const uint4*)W1hi; uint4* s1 = (uint4*)sW1hi;
    const uint4* g2 = (const uint4*)W1lo; uint4* s2 = (uint4*)sW1lo;
    for (int i = tid; i < 64*PK1/8; i += 256) { s1[i] = g1[i]; s2[i] = g2[i]; }
  }
  int lane = tid & 63, wave = tid >> 6;
  int l15 = lane & 15, quad = lane >> 4;

  s16x8 w2h[2][4], w2l[2][4];
  #pragma unroll
  for (int kb = 0; kb < 2; kb++)
    #pragma unroll
    for (int ct = 0; ct < 4; ct++) {
      int off = (ct*16 + l15)*PK2 + kb*32 + quad*8;
      w2h[kb][ct] = *(const s16x8*)(W2hi + off);
      w2l[kb][ct] = *(const s16x8*)(W2lo + off);
    }
  float b1v[4], b2v[4];
  #pragma unroll
  for (int ct = 0; ct < 4; ct++) { b1v[ct] = b1[ct*16+l15]; b2v[ct] = b2[ct*16+l15]; }
  __syncthreads();

  ushort_t* myMh = sMh[wave];
  ushort_t* myMl = sMl[wave];

  for (int base = blockIdx.x * 128; base < NNODES; base += gridDim.x * 128) {
    int e0 = base + wave * 32;

    s16x8 ah[2][4], al[2][4];
    #pragma unroll
    for (int rt = 0; rt < 2; rt++) {
      int em = e0 + rt*16 + l15;
      #pragma unroll
      for (int kb = 0; kb < 2; kb++) {
        int off = em*64 + kb*32 + quad*8;
        ah[rt][kb] = *(const s16x8*)(Ahi + off);
        al[rt][kb] = *(const s16x8*)(Alo + off);
      }
      #pragma unroll
      for (int kb = 2; kb < 4; kb++) {
        int off = em*64 + (kb & 1)*32 + quad*8;
        float4 v0 = *(const float4*)(aggF + off);
        float4 v1 = *(const float4*)(aggF + off + 4);
        float vv[8] = {v0.x,v0.y,v0.z,v0.w,v1.x,v1.y,v1.z,v1.w};
        s16x8 hh, ll;
        #pragma unroll
        for (int j = 0; j < 8; j++) {
          unsigned short hb = f2bf(vv[j]);
          hh[j] = (short)hb;
          ll[j] = (short)f2bf(vv[j] - bf2f(hb));
        }
        ah[rt][kb] = hh; al[rt][kb] = ll;
      }
    }

    f32x4 acc[2][4];
    #pragma unroll
    for (int rt = 0; rt < 2; rt++)
      #pragma unroll
      for (int ct = 0; ct < 4; ct++)
        acc[rt][ct] = (f32x4){0.f, 0.f, 0.f, 0.f};

    #pragma unroll
    for (int kb = 0; kb < 4; kb++)
      #pragma unroll
      for (int ct = 0; ct < 4; ct++) {
        int woff = (ct*16 + l15)*PK1 + kb*32 + quad*8;
        s16x8 bh = *(const s16x8*)&sW1hi[woff];
        s16x8 bl = *(const s16x8*)&sW1lo[woff];
        #pragma unroll
        for (int rt = 0; rt < 2; rt++) {
          acc[rt][ct] = __builtin_amdgcn_mfma_f32_16x16x32_bf16(al[rt][kb], bl, acc[rt][ct], 0, 0, 0);
          acc[rt][ct] = __builtin_amdgcn_mfma_f32_16x16x32_bf16(al[rt][kb], bh, acc[rt][ct], 0, 0, 0);
          acc[rt][ct] = __builtin_amdgcn_mfma_f32_16x16x32_bf16(ah[rt][kb], bl, acc[rt][ct], 0, 0, 0);
          acc[rt][ct] = __builtin_amdgcn_mfma_f32_16x16x32_bf16(ah[rt][kb], bh, acc[rt][ct], 0, 0, 0);
        }
      }

    #pragma unroll
    for (int rt = 0; rt < 2; rt++)
      #pragma unroll
      for (int ct = 0; ct < 4; ct++)
        #pragma unroll
        for (int r = 0; r < 4; r++) {
          float v = fmaxf(acc[rt][ct][r] + b1v[ct], 0.f);
          unsigned short hb = f2bf(v);
          int idx = (rt*16 + quad*4 + r)*PK2 + ct*16 + l15;
          myMh[idx] = hb;
          myMl[idx] = f2bf(v - bf2f(hb));
        }

    f32x4 facc[2][4];
    #pragma unroll
    for (int rt = 0; rt < 2; rt++)
      #pragma unroll
      for (int ct = 0; ct < 4; ct++)
        facc[rt][ct] = (f32x4){0.f, 0.f, 0.f, 0.f};

    #pragma unroll
    for (int kb = 0; kb < 2; kb++) {
      s16x8 mhf[2], mlf[2];
      #pragma unroll
      for (int rt = 0; rt < 2; rt++) {
        int idx = (rt*16 + l15)*PK2 + kb*32 + quad*8;
        mhf[rt] = *(const s16x8*)&myMh[idx];
        mlf[rt] = *(const s16x8*)&myMl[idx];
      }
      #pragma unroll
      for (int ct = 0; ct < 4; ct++)
        #pragma unroll
        for (int rt = 0; rt < 2; rt++) {
          facc[rt][ct] = __builtin_amdgcn_mfma_f32_16x16x32_bf16(mlf[rt], w2l[kb][ct], facc[rt][ct], 0, 0, 0);
          facc[rt][ct] = __builtin_amdgcn_mfma_f32_16x16x32_bf16(mlf[rt], w2h[kb][ct], facc[rt][ct], 0, 0, 0);
          facc[rt][ct] = __builtin_amdgcn_mfma_f32_16x16x32_bf16(mhf[rt], w2l[kb][ct], facc[rt][ct], 0, 0, 0);
          facc[rt][ct] = __builtin_amdgcn_mfma_f32_16x16x32_bf16(mhf[rt], w2h[kb][ct], facc[rt][ct], 0, 0, 0);
        }
    }

    #pragma unroll
    for (int rt = 0; rt < 2; rt++)
      #pragma unroll
      for (int r = 0; r < 4; r++) {
        int grow = e0 + rt*16 + quad*4 + r;
        #pragma unroll
        for (int ct = 0; ct < 4; ct++) {
          float v = fmaxf(facc[rt][ct][r] + b2v[ct], 0.f);
          out[(size_t)grow*64 + ct*16 + l15] = v;
        }
      }
  }
}

// ------------- InstanceNorm, 3 phases -------------
__global__ __launch_bounds__(1024) void in_partial_kernel(
    const float* __restrict__ u, float* __restrict__ pA, float* __restrict__ pB)
{
  int g = blockIdx.x >> 3, sb = blockIdx.x & 7;
  int c = threadIdx.x & 63, rg = threadIdx.x >> 6;
  const float* ub = u + ((size_t)g * NSAMP + sb * 256) * 64;
  float s = 0.f, s2 = 0.f;
  for (int i = rg; i < 256; i += 16) {
    float v = ub[i*64 + c];
    s += v; s2 += v*v;
  }
  __shared__ float ps[16][64], ps2[16][64];
  ps[rg][c] = s; ps2[rg][c] = s2;
  __syncthreads();
  if (rg == 0) {
    float a = 0.f, b = 0.f;
    #pragma unroll
    for (int j = 0; j < 16; j++) { a += ps[j][c]; b += ps2[j][c]; }
    pA[(g*8+sb)*64 + c] = a;
    pB[(g*8+sb)*64 + c] = b;
  }
}

__global__ __launch_bounds__(64) void in_finalize_kernel(
    const float* __restrict__ pA, const float* __restrict__ pB,
    float* __restrict__ mean, float* __restrict__ rstd)
{
  int g = blockIdx.x, c = threadIdx.x;
  float a = 0.f, b = 0.f;
  for (int j = 0; j < 8; j++) { a += pA[(g*8+j)*64 + c]; b += pB[(g*8+j)*64 + c]; }
  float m = a * (1.f / NSAMP);
  float var = b * (1.f / NSAMP) - m * m;
  mean[g*64 + c] = m;
  rstd[g*64 + c] = rsqrtf(var + EPS);
}

__global__ __launch_bounds__(256) void in_apply_kernel(
    const float* __restrict__ u, const float* __restrict__ mean,
    const float* __restrict__ rstd, float* __restrict__ hf,
    ushort_t* __restrict__ hhi, ushort_t* __restrict__ hlo)
{
  int idx = blockIdx.x * 256 + threadIdx.x;   // n*64 + c
  int c = idx & 63, g = idx >> 17;
  float v = (u[idx] - mean[g*64 + c]) * rstd[g*64 + c];
  hf[idx] = v;
  unsigned short hb = f2bf(v);
  hhi[idx] = hb;
  hlo[idx] = f2bf(v - bf2f(hb));
}

// ------------- decoder + unit normalize -------------
__global__ __launch_bounds__(64) void decoder_kernel(
    const float* __restrict__ h, const float* __restrict__ W,
    const float* __restrict__ b, float* __restrict__ X)
{
  __shared__ float sh[64][65];
  int lane = threadIdx.x;
  int nb = blockIdx.x * 64;
  for (int r = 0; r < 64; r++) sh[r][lane] = h[(size_t)(nb + r) * 64 + lane];
  __syncthreads();
  float a0 = b[0], a1 = b[1], a2 = b[2];
  #pragma unroll
  for (int c = 0; c < 64; c++) {
    float v = sh[lane][c];
    a0 = fmaf(v, W[c*3+0], a0);
    a1 = fmaf(v, W[c*3+1], a1);
    a2 = fmaf(v, W[c*3+2], a2);
  }
  float inv = 1.f / sqrtf(a0*a0 + a1*a1 + a2*a2);
  int n = nb + lane;
  X[n*3+0] = a0 * inv;
  X[n*3+1] = a1 * inv;
  X[n*3+2] = a2 * inv;
}

// ------------- MMD -------------
__device__ inline float block_reduce_sum(float v) {
  #pragma unroll
  for (int o = 32; o > 0; o >>= 1) v += __shfl_down(v, o, 64);
  __shared__ float red[4];
  int lane = threadIdx.x & 63, w = threadIdx.x >> 6;
  if (lane == 0) red[w] = v;
  __syncthreads();
  float t = 0.f;
  if (threadIdx.x == 0) t = red[0] + red[1] + red[2] + red[3];
  return t;
}

__global__ __launch_bounds__(256) void kxx_kernel(
    const float* __restrict__ X, float* __restrict__ kxx)
{
  int b  = blockIdx.x >> 5;
  int nt = blockIdx.x & 31;
  const float* Xb = X + (size_t)b * NSAMP * 3;
  __shared__ float sx[192];
  if (threadIdx.x < 192) sx[threadIdx.x] = Xb[nt*192 + threadIdx.x];
  __syncthreads();
  float ps = 0.f;
  for (int it = 0; it < 8; it++) {
    int m = it*256 + threadIdx.x;
    float x0 = Xb[m*3+0], x1 = Xb[m*3+1], x2 = Xb[m*3+2];
    #pragma unroll
    for (int n = 0; n < 64; n++) {
      float d = x0*sx[n*3+0] + x1*sx[n*3+1] + x2*sx[n*3+2];
      ps += __expf(2.f*d - 2.f);
    }
  }
  float t = block_reduce_sum(ps);
  if (threadIdx.x == 0) atomicAdd(&kxx[b], t);
}

__global__ __launch_bounds__(256) void kxy_kernel(
    const float* __restrict__ X, YArr Y, float* __restrict__ kxy)
{
  int b = blockIdx.x;
  const float* Xb = X + (size_t)b * NSAMP * 3;
  float ps = 0.f;
  for (int it = 0; it < 8; it++) {
    int n = it*256 + threadIdx.x;
    float x0 = Xb[n*3+0], x1 = Xb[n*3+1], x2 = Xb[n*3+2];
    #pragma unroll
    for (int m = 0; m < 64; m++) {
      float d = x0*Y.v[m*3+0] + x1*Y.v[m*3+1] + x2*Y.v[m*3+2];
      ps += __expf(2.f*d - 2.f);
    }
  }
  float t = block_reduce_sum(ps);
  if (threadIdx.x == 0) kxy[b] = t;
}

__global__ void loss_kernel(const float* __restrict__ kxx,
                            const float* __restrict__ kxy,
                            float kyy, float* __restrict__ out)
{
  if (threadIdx.x == 0 && blockIdx.x == 0) {
    float s = 0.f;
    for (int b = 0; b < NBATCH; b++)
      s += kxx[b] * (1.0f/((float)NSAMP*(float)NSAMP))
         - 2.0f * kxy[b] * (1.0f/((float)NSAMP*64.0f));
    out[0] = s * (1.0f/NBATCH) + kyy;
  }
}

// ------------- launch -------------
extern "C" void kernel_launch(void* const* d_in, const int* in_sizes, int n_in,
                              void* d_out, int out_size, void* d_ws, size_t ws_size,
                              hipStream_t stream)
{
  const float* x    = (const float*)d_in[0];
  const int*   esrc = (const int*)  d_in[1];
  const int*   edst = (const int*)  d_in[2];
  const float* encW = (const float*)d_in[4];
  const float* encb = (const float*)d_in[5];
  const float* m1W  = (const float*)d_in[6];
  const float* m1b  = (const float*)d_in[7];
  const float* m2W  = (const float*)d_in[8];
  const float* m2b  = (const float*)d_in[9];
  const float* u1W  = (const float*)d_in[10];
  const float* u1b  = (const float*)d_in[11];
  const float* u2W  = (const float*)d_in[12];
  const float* u2b  = (const float*)d_in[13];
  const float* decW = (const float*)d_in[14];
  const float* decb = (const float*)d_in[15];
  float* out = (float*)d_out;

  const size_t NF = (size_t)NNODES * 64;
  float* h_f   = (float*)d_ws;
  float* agg   = h_f + NF;
  float* u_buf = agg + NF;
  float* Pbuf  = u_buf + NF;
  float* Qbuf  = Pbuf + NF;
  float* kxx   = Qbuf + NF;
  float* kxy   = kxx + 16;
  float* pA    = kxy + 16;
  float* pB    = pA + 16*8*64;
  float* meanb = pB + 16*8*64;
  float* rstdb = meanb + 16*64;
  int* icnt    = (int*)(rstdb + 16*64);
  int* ioffs   = icnt + NNODES;
  int* icur    = ioffs + NNODES;
  int* psrc    = icur + NNODES;
  int* pdst    = psrc + NEDGES;
  ushort_t* us = (ushort_t*)(pdst + NEDGES);
  ushort_t* h_hi   = us;  us += NF;
  ushort_t* h_lo   = us;  us += NF;
  ushort_t* wce_hi = us;  us += 4*128*PK2;
  ushort_t* wce_lo = us;  us += 4*128*PK2;
  ushort_t* w2e_hi = us;  us += 4*64*PK2;
  ushort_t* w2e_lo = us;  us += 4*64*PK2;
  ushort_t* w1n_hi = us;  us += 4*64*PK1;
  ushort_t* w1n_lo = us;  us += 4*64*PK1;
  ushort_t* w2n_hi = us;  us += 4*64*PK2;
  ushort_t* w2n_lo = us;  us += 4*64*PK2;

  float* X = out + 1;

  prep_weights_kernel<<<384, 256, 0, stream>>>(
      m1W, m2W, u1W, u2W,
      wce_hi, wce_lo, w2e_hi, w2e_lo, w1n_hi, w1n_lo, w2n_hi, w2n_lo);

  encoder_kernel<<<NNODES*64/256, 256, 0, stream>>>(x, encW, encb, h_f, h_hi, h_lo);

  hipMemsetAsync(icnt, 0, NNODES * sizeof(int), stream);
  count_kernel<<<NEDGES/256, 256, 0, stream>>>(edst, icnt);
  scan_kernel<<<1, 1024, 0, stream>>>(icnt, ioffs, icur);
  fill_kernel<<<NEDGES/256, 256, 0, stream>>>(esrc, edst, icur, psrc, pdst);

  for (int l = 0; l < 4; l++) {
    pq_kernel<<<256, 256, 0, stream>>>(
        h_hi, h_lo, wce_hi + (size_t)l*128*PK2, wce_lo + (size_t)l*128*PK2,
        Pbuf, Qbuf);
    hipMemsetAsync(agg, 0, NF * sizeof(float), stream);
    edge_fused_kernel<<<768, 256, 0, stream>>>(
        Pbuf, Qbuf, psrc, pdst, m1b + l*64,
        w2e_hi + (size_t)l*64*PK2, w2e_lo + (size_t)l*64*PK2, m2b + l*64,
        agg);
    node_mfma_kernel<<<256, 256, 0, stream>>>(
        h_hi, h_lo, agg,
        w1n_hi + (size_t)l*64*PK1, w1n_lo + (size_t)l*64*PK1, u1b + l*64,
        w2n_hi + (size_t)l*64*PK2, w2n_lo + (size_t)l*64*PK2, u2b + l*64,
        u_buf);
    in_partial_kernel<<<NBATCH*8, 1024, 0, stream>>>(u_buf, pA, pB);
    in_finalize_kernel<<<NBATCH, 64, 0, stream>>>(pA, pB, meanb, rstdb);
    in_apply_kernel<<<NNODES*64/256, 256, 0, stream>>>(u_buf, meanb, rstdb, h_f, h_hi, h_lo);
  }

  decoder_kernel<<<NNODES/64, 64, 0, stream>>>(h_f, decW, decb, X);

  hipMemsetAsync(kxx, 0, 16 * sizeof(float), stream);
  kxx_kernel<<<NBATCH*32, 256, 0, stream>>>(X, kxx);

  YArr Y;
  {
    const double pi = 3.14159265358979323846;
    double phi = pi * (3.0 - sqrt(5.0));
    for (int i = 0; i < 64; i++) {
      double y  = 1.0 - 2.0 * (double)i / 63.0;
      double r  = sqrt(fmax(0.0, 1.0 - y*y));
      double th = phi * (double)i;
      Y.v[i*3+0] = (float)(cos(th) * r);
      Y.v[i*3+1] = (float)y;
      Y.v[i*3+2] = (float)(sin(th) * r);
    }
  }
  double kyy_acc = 0.0;
  for (int i = 0; i < 64; i++)
    for (int j = 0; j < 64; j++) {
      double d = (double)Y.v[i*3+0]*Y.v[j*3+0]
               + (double)Y.v[i*3+1]*Y.v[j*3+1]
               + (double)Y.v[i*3+2]*Y.v[j*3+2];
      kyy_acc += exp(2.0*d - 2.0);
    }
  float kyy = (float)(kyy_acc / 4096.0);

  kxy_kernel<<<NBATCH, 256, 0, stream>>>(X, Y, kxy);
  loss_kernel<<<1, 64, 0, stream>>>(kxx, kxy, kyy, out);
}

// Round 5
// 448.993 us; speedup vs baseline: 4.4982x; 1.1538x over previous
//
#include <hip/hip_runtime.h>
#include <cmath>

#define NNODES 32768
#define NEDGES 524288
#define NBATCH 16
#define NSAMP  2048
#define EPS    1e-5f

#define PK2 72    // 64 + 8 pad (shorts); row stride 144 B (16B-multiple)

typedef short s16x8 __attribute__((ext_vector_type(8)));
typedef float f32x4 __attribute__((ext_vector_type(4)));
typedef unsigned short ushort_t;

struct YArr { float v[192]; };

static __device__ __forceinline__ unsigned short f2bf(float f) {
  unsigned int u = __float_as_uint(f);
  u = (u + 0x7fffu + ((u >> 16) & 1u)) >> 16;   // RN-even
  return (unsigned short)u;
}
static __device__ __forceinline__ float bf2f(unsigned short b) {
  return __uint_as_float(((unsigned int)b) << 16);
}

// ------------- weight prep -------------
// Wcomb [l][j 0..191][PK2]: j<64 P (m1W rows 0..63), j<128 Q (m1W rows 64..127),
//                           j<192 R (u1W rows 0..63)
// W1b   [l][j 0..63][PK2]: u1W rows 64..127 (agg input)
// W2e   [l][j][PK2] from m2W;  W2n [l][j][PK2] from u2W
__global__ __launch_bounds__(256) void prep_weights_kernel(
    const float* __restrict__ m1W, const float* __restrict__ m2W,
    const float* __restrict__ u1W, const float* __restrict__ u2W,
    ushort_t* __restrict__ wc_hi, ushort_t* __restrict__ wc_lo,
    ushort_t* __restrict__ w1b_hi, ushort_t* __restrict__ w1b_lo,
    ushort_t* __restrict__ w2e_hi, ushort_t* __restrict__ w2e_lo,
    ushort_t* __restrict__ w2n_hi, ushort_t* __restrict__ w2n_lo)
{
  int t = blockIdx.x * 256 + threadIdx.x;
  if (t >= 4 * 24576) return;
  int l = t / 24576;
  int r = t % 24576;
  float w; ushort_t *dh, *dl;
  if (r < 12288) {                      // Wcomb
    int j = r >> 6, k = r & 63;
    if (j < 64)       w = m1W[l*8192 + k*64 + j];
    else if (j < 128) w = m1W[l*8192 + (64 + k)*64 + (j - 64)];
    else              w = u1W[l*8192 + k*64 + (j - 128)];
    int off = l*192*PK2 + j*PK2 + k;
    dh = wc_hi + off; dl = wc_lo + off;
  } else if (r < 16384) {               // W1b
    int idx = r - 12288;
    int j = idx & 63, k = idx >> 6;
    w = u1W[l*8192 + (64 + k)*64 + j];
    int off = l*64*PK2 + j*PK2 + k;
    dh = w1b_hi + off; dl = w1b_lo + off;
  } else if (r < 20480) {               // W2e
    int idx = r - 16384;
    int j = idx & 63, k = idx >> 6;
    w = m2W[l*4096 + k*64 + j];
    int off = l*64*PK2 + j*PK2 + k;
    dh = w2e_hi + off; dl = w2e_lo + off;
  } else {                              // W2n
    int idx = r - 20480;
    int j = idx & 63, k = idx >> 6;
    w = u2W[l*4096 + k*64 + j];
    int off = l*64*PK2 + j*PK2 + k;
    dh = w2n_hi + off; dl = w2n_lo + off;
  }
  unsigned short hb = f2bf(w);
  *dh = hb;
  *dl = f2bf(w - bf2f(hb));
}

// ------------- CSR build -------------
__global__ __launch_bounds__(256) void count_kernel(const int* __restrict__ edst,
                                                    int* __restrict__ cnt) {
  int e = blockIdx.x * 256 + threadIdx.x;
  if (e < NEDGES) atomicAdd(&cnt[edst[e]], 1);
}

__global__ __launch_bounds__(1024) void scan_kernel(const int* __restrict__ cnt,
                                                    int* __restrict__ offs,
                                                    int* __restrict__ cursor) {
  __shared__ int sc[1024];
  int tid = threadIdx.x;
  int base = tid * 32;
  int s = 0;
  #pragma unroll
  for (int i = 0; i < 32; i++) s += cnt[base + i];
  sc[tid] = s; __syncthreads();
  int own = s;
  for (int off = 1; off < 1024; off <<= 1) {
    int v = (tid >= off) ? sc[tid - off] : 0;
    __syncthreads();
    sc[tid] += v;
    __syncthreads();
  }
  int run = sc[tid] - own;
  for (int i = 0; i < 32; i++) {
    offs[base + i] = run; cursor[base + i] = run;
    run += cnt[base + i];
  }
}

__global__ __launch_bounds__(256) void fill_kernel(
    const int* __restrict__ esrc, const int* __restrict__ edst,
    int* __restrict__ cursor, int* __restrict__ psrc, int* __restrict__ pdst) {
  int e = blockIdx.x * 256 + threadIdx.x;
  if (e < NEDGES) {
    int d = edst[e];
    int pos = atomicAdd(&cursor[d], 1);
    psrc[pos] = esrc[e];
    pdst[pos] = d;
  }
}

// ------------- fused (encode|norm) + P|Q|R GEMM -------------
// MODE 0: rows h = x@encW+encb (layer 0). MODE 1: h = (u-mean)*rstd.
// Wave handles 16 rows; h split hi/lo via wave-private LDS; [16,64]@[64,192]
// 4-product MFMA with B-fragments streamed from global (L2-hot).
template<int MODE>
__global__ __launch_bounds__(256) void norm_pqr_kernel(
    const float* __restrict__ in,     // x (MODE 0) or u (MODE 1)
    const float* __restrict__ sA, const float* __restrict__ sB,
    const float* __restrict__ encW, const float* __restrict__ encb,
    const ushort_t* __restrict__ Wh, const ushort_t* __restrict__ Wl,
    float* __restrict__ P, float* __restrict__ Q, float* __restrict__ Rb)
{
  __shared__ __align__(16) ushort_t sAh[4][16*PK2];
  __shared__ __align__(16) ushort_t sAl[4][16*PK2];
  int tid = threadIdx.x, lane = tid & 63, wave = tid >> 6;
  int l15 = lane & 15, quad = lane >> 4;
  int base = blockIdx.x * 64 + wave * 16;
  int g = blockIdx.x >> 5;

  float mean = 0.f, rstd = 1.f, w0 = 0.f, w1 = 0.f, w2 = 0.f, bb = 0.f;
  if (MODE) {
    float a = sA[g*64 + lane], q = sB[g*64 + lane];
    mean = a * (1.f / NSAMP);
    float var = q * (1.f / NSAMP) - mean * mean;
    rstd = rsqrtf(var + EPS);
  } else {
    w0 = encW[lane]; w1 = encW[64 + lane]; w2 = encW[128 + lane];
    bb = encb[lane];
  }

  ushort_t* ah_s = sAh[wave];
  ushort_t* al_s = sAl[wave];
  #pragma unroll
  for (int r = 0; r < 16; r++) {
    int n = base + r;
    float v;
    if (MODE) v = (in[(size_t)n*64 + lane] - mean) * rstd;
    else      v = fmaf(in[n*3+2], w2, fmaf(in[n*3+1], w1, fmaf(in[n*3+0], w0, bb)));
    unsigned short hb = f2bf(v);
    ah_s[r*PK2 + lane] = hb;
    al_s[r*PK2 + lane] = f2bf(v - bf2f(hb));
  }

  s16x8 ah[2], al[2];
  #pragma unroll
  for (int kb = 0; kb < 2; kb++) {
    int idx = l15*PK2 + kb*32 + quad*8;
    ah[kb] = *(const s16x8*)&ah_s[idx];
    al[kb] = *(const s16x8*)&al_s[idx];
  }

  #pragma unroll
  for (int ct = 0; ct < 12; ct++) {
    f32x4 acc = (f32x4){0.f, 0.f, 0.f, 0.f};
    #pragma unroll
    for (int kb = 0; kb < 2; kb++) {
      int woff = (ct*16 + l15)*PK2 + kb*32 + quad*8;
      s16x8 bh = *(const s16x8*)(Wh + woff);
      s16x8 bl = *(const s16x8*)(Wl + woff);
      acc = __builtin_amdgcn_mfma_f32_16x16x32_bf16(al[kb], bl, acc, 0, 0, 0);
      acc = __builtin_amdgcn_mfma_f32_16x16x32_bf16(al[kb], bh, acc, 0, 0, 0);
      acc = __builtin_amdgcn_mfma_f32_16x16x32_bf16(ah[kb], bl, acc, 0, 0, 0);
      acc = __builtin_amdgcn_mfma_f32_16x16x32_bf16(ah[kb], bh, acc, 0, 0, 0);
    }
    int j = ct*16 + l15;
    float* dst; int jj;
    if (ct < 4)      { dst = P;  jj = j; }
    else if (ct < 8) { dst = Q;  jj = j - 64; }
    else             { dst = Rb; jj = j - 128; }
    #pragma unroll
    for (int rr = 0; rr < 4; rr++) {
      int row = base + quad*4 + rr;
      dst[(size_t)row*64 + jj] = acc[rr];
    }
  }
}

// ------------- fused edge MLP + segment-reduce (unchanged from R4) -------------
__global__ __launch_bounds__(256, 3) void edge_fused_kernel(
    const float* __restrict__ Pbuf, const float* __restrict__ Qbuf,
    const int* __restrict__ psrc, const int* __restrict__ pdst,
    const float* __restrict__ b1,
    const ushort_t* __restrict__ W2hi, const ushort_t* __restrict__ W2lo,
    const float* __restrict__ b2,
    float* __restrict__ agg)
{
  __shared__ __align__(16) char smem[4][9216];
  __shared__ int  sSD[4][64];

  int tid = threadIdx.x;
  int lane = tid & 63, wave = tid >> 6;
  int l15 = lane & 15, quad = lane >> 4;

  ushort_t* mh = (ushort_t*)smem[wave];
  ushort_t* ml = mh + 32*PK2;
  float*    m2 = (float*)smem[wave];

  s16x8 w2h[2][4], w2l[2][4];
  #pragma unroll
  for (int kb = 0; kb < 2; kb++)
    #pragma unroll
    for (int ct = 0; ct < 4; ct++) {
      int off = (ct*16 + l15)*PK2 + kb*32 + quad*8;
      w2h[kb][ct] = *(const s16x8*)(W2hi + off);
      w2l[kb][ct] = *(const s16x8*)(W2lo + off);
    }
  float b1v = b1[lane];
  float b2v[4];
  #pragma unroll
  for (int ct = 0; ct < 4; ct++) b2v[ct] = b2[ct*16 + l15];

  for (int base = blockIdx.x * 128; base < NEDGES; base += gridDim.x * 128) {
    int e0 = base + wave * 32;

    {
      const int* tb = (lane < 32) ? psrc : pdst;
      int i = (lane < 32) ? (e0 + lane) : (e0 + lane - 32);
      sSD[wave][lane] = tb[i];
    }

    #pragma unroll
    for (int rb = 0; rb < 4; rb++) {
      float pv[8], qv[8];
      #pragma unroll
      for (int i = 0; i < 8; i++) {
        int r = rb*8 + i;
        int s = sSD[wave][r];
        int d = sSD[wave][32 + r];
        qv[i] = Qbuf[(s << 6) + lane];
        pv[i] = Pbuf[(d << 6) + lane];
      }
      #pragma unroll
      for (int i = 0; i < 8; i++) {
        int r = rb*8 + i;
        float v = fmaxf(pv[i] + qv[i] + b1v, 0.f);
        unsigned short hb = f2bf(v);
        mh[r*PK2 + lane] = hb;
        ml[r*PK2 + lane] = f2bf(v - bf2f(hb));
      }
    }

    f32x4 facc[2][4];
    #pragma unroll
    for (int rt = 0; rt < 2; rt++)
      #pragma unroll
      for (int ct = 0; ct < 4; ct++)
        facc[rt][ct] = (f32x4){0.f, 0.f, 0.f, 0.f};

    #pragma unroll
    for (int kb = 0; kb < 2; kb++) {
      s16x8 mhf[2], mlf[2];
      #pragma unroll
      for (int rt = 0; rt < 2; rt++) {
        int idx = (rt*16 + l15)*PK2 + kb*32 + quad*8;
        mhf[rt] = *(const s16x8*)&mh[idx];
        mlf[rt] = *(const s16x8*)&ml[idx];
      }
      #pragma unroll
      for (int ct = 0; ct < 4; ct++)
        #pragma unroll
        for (int rt = 0; rt < 2; rt++) {
          facc[rt][ct] = __builtin_amdgcn_mfma_f32_16x16x32_bf16(mlf[rt], w2l[kb][ct], facc[rt][ct], 0, 0, 0);
          facc[rt][ct] = __builtin_amdgcn_mfma_f32_16x16x32_bf16(mlf[rt], w2h[kb][ct], facc[rt][ct], 0, 0, 0);
          facc[rt][ct] = __builtin_amdgcn_mfma_f32_16x16x32_bf16(mhf[rt], w2l[kb][ct], facc[rt][ct], 0, 0, 0);
          facc[rt][ct] = __builtin_amdgcn_mfma_f32_16x16x32_bf16(mhf[rt], w2h[kb][ct], facc[rt][ct], 0, 0, 0);
        }
    }

    #pragma unroll
    for (int rt = 0; rt < 2; rt++)
      #pragma unroll
      for (int ct = 0; ct < 4; ct++)
        #pragma unroll
        for (int r = 0; r < 4; r++)
          m2[(rt*16 + quad*4 + r)*68 + ct*16 + l15] = fmaxf(facc[rt][ct][r] + b2v[ct], 0.f);

    int curd = sSD[wave][32];
    float acc = 0.f;
    #pragma unroll
    for (int r = 0; r < 32; r++) {
      int d = sSD[wave][32 + r];
      float v = m2[r*68 + lane];
      if (d != curd) {
        unsafeAtomicAdd(&agg[(curd << 6) + lane], acc);
        acc = 0.f; curd = d;
      }
      acc += v;
    }
    unsafeAtomicAdd(&agg[(curd << 6) + lane], acc);
  }
}

// ------------- node MLP: u = relu((relu(R + agg@W1b + b1)) @ W2 + b2) ------
// 16-row wave tiles; stats (sum, sumsq per graph-channel) accumulated in epilogue.
__global__ __launch_bounds__(256) void node_mfma_kernel(
    const float* __restrict__ aggF, const float* __restrict__ Rbuf,
    const ushort_t* __restrict__ W1h, const ushort_t* __restrict__ W1l,
    const float* __restrict__ b1,
    const ushort_t* __restrict__ W2h, const ushort_t* __restrict__ W2l,
    const float* __restrict__ b2,
    float* __restrict__ uout, float* __restrict__ sA, float* __restrict__ sB)
{
  __shared__ __align__(16) ushort_t sMh[4][16*PK2];
  __shared__ __align__(16) ushort_t sMl[4][16*PK2];
  int tid = threadIdx.x, lane = tid & 63, wave = tid >> 6;
  int l15 = lane & 15, quad = lane >> 4;
  int base = blockIdx.x * 64 + wave * 16;
  int g = blockIdx.x >> 5;

  // A fragments from agg (fp32 -> hi/lo in registers)
  s16x8 ah[2], al[2];
  {
    int em = base + l15;
    #pragma unroll
    for (int kb = 0; kb < 2; kb++) {
      int off = em*64 + kb*32 + quad*8;
      float4 v0 = *(const float4*)(aggF + off);
      float4 v1 = *(const float4*)(aggF + off + 4);
      float vv[8] = {v0.x,v0.y,v0.z,v0.w,v1.x,v1.y,v1.z,v1.w};
      s16x8 hh, ll;
      #pragma unroll
      for (int j = 0; j < 8; j++) {
        unsigned short hb = f2bf(vv[j]);
        hh[j] = (short)hb;
        ll[j] = (short)f2bf(vv[j] - bf2f(hb));
      }
      ah[kb] = hh; al[kb] = ll;
    }
  }

  ushort_t* mh = sMh[wave];
  ushort_t* ml = sMl[wave];
  float b1v[4], b2v[4];
  #pragma unroll
  for (int ct = 0; ct < 4; ct++) { b1v[ct] = b1[ct*16+l15]; b2v[ct] = b2[ct*16+l15]; }

  // layer 1
  #pragma unroll
  for (int ct = 0; ct < 4; ct++) {
    f32x4 acc = (f32x4){0.f, 0.f, 0.f, 0.f};
    #pragma unroll
    for (int kb = 0; kb < 2; kb++) {
      int woff = (ct*16 + l15)*PK2 + kb*32 + quad*8;
      s16x8 bh = *(const s16x8*)(W1h + woff);
      s16x8 bl = *(const s16x8*)(W1l + woff);
      acc = __builtin_amdgcn_mfma_f32_16x16x32_bf16(al[kb], bl, acc, 0, 0, 0);
      acc = __builtin_amdgcn_mfma_f32_16x16x32_bf16(al[kb], bh, acc, 0, 0, 0);
      acc = __builtin_amdgcn_mfma_f32_16x16x32_bf16(ah[kb], bl, acc, 0, 0, 0);
      acc = __builtin_amdgcn_mfma_f32_16x16x32_bf16(ah[kb], bh, acc, 0, 0, 0);
    }
    int j = ct*16 + l15;
    #pragma unroll
    for (int rr = 0; rr < 4; rr++) {
      int row = quad*4 + rr;
      float v = acc[rr] + Rbuf[(size_t)(base+row)*64 + j] + b1v[ct];
      v = fmaxf(v, 0.f);
      unsigned short hb = f2bf(v);
      mh[row*PK2 + j] = hb;
      ml[row*PK2 + j] = f2bf(v - bf2f(hb));
    }
  }

  // layer 2
  s16x8 mhf[2], mlf[2];
  #pragma unroll
  for (int kb = 0; kb < 2; kb++) {
    int idx = l15*PK2 + kb*32 + quad*8;
    mhf[kb] = *(const s16x8*)&mh[idx];
    mlf[kb] = *(const s16x8*)&ml[idx];
  }
  #pragma unroll
  for (int ct = 0; ct < 4; ct++) {
    f32x4 facc = (f32x4){0.f, 0.f, 0.f, 0.f};
    #pragma unroll
    for (int kb = 0; kb < 2; kb++) {
      int woff = (ct*16 + l15)*PK2 + kb*32 + quad*8;
      s16x8 bh = *(const s16x8*)(W2h + woff);
      s16x8 bl = *(const s16x8*)(W2l + woff);
      facc = __builtin_amdgcn_mfma_f32_16x16x32_bf16(mlf[kb], bl, facc, 0, 0, 0);
      facc = __builtin_amdgcn_mfma_f32_16x16x32_bf16(mlf[kb], bh, facc, 0, 0, 0);
      facc = __builtin_amdgcn_mfma_f32_16x16x32_bf16(mhf[kb], bl, facc, 0, 0, 0);
      facc = __builtin_amdgcn_mfma_f32_16x16x32_bf16(mhf[kb], bh, facc, 0, 0, 0);
    }
    int j = ct*16 + l15;
    float s = 0.f, s2 = 0.f;
    #pragma unroll
    for (int rr = 0; rr < 4; rr++) {
      int row = quad*4 + rr;
      float v = fmaxf(facc[rr] + b2v[ct], 0.f);
      uout[(size_t)(base+row)*64 + j] = v;
      s += v; s2 += v*v;
    }
    s  += __shfl_xor(s, 16);  s  += __shfl_xor(s, 32);
    s2 += __shfl_xor(s2, 16); s2 += __shfl_xor(s2, 32);
    if (quad == 0) {
      unsafeAtomicAdd(&sA[g*64 + j], s);
      unsafeAtomicAdd(&sB[g*64 + j], s2);
    }
  }
}

// ------------- decoder: norm + [64]->3 + unit normalize -------------
__global__ __launch_bounds__(64) void decoder_kernel(
    const float* __restrict__ u, const float* __restrict__ sA,
    const float* __restrict__ sB, const float* __restrict__ W,
    const float* __restrict__ b, float* __restrict__ X)
{
  __shared__ float sh[64][65];
  __shared__ float sm[64], sr[64];
  int lane = threadIdx.x;
  int nb = blockIdx.x * 64;
  int g = blockIdx.x >> 5;
  {
    float a = sA[g*64 + lane], q = sB[g*64 + lane];
    float mean = a * (1.f / NSAMP);
    float var = q * (1.f / NSAMP) - mean * mean;
    sm[lane] = mean;
    sr[lane] = rsqrtf(var + EPS);
  }
  for (int r = 0; r < 64; r++) sh[r][lane] = u[(size_t)(nb + r) * 64 + lane];
  __syncthreads();
  float a0 = b[0], a1 = b[1], a2 = b[2];
  #pragma unroll
  for (int c = 0; c < 64; c++) {
    float v = (sh[lane][c] - sm[c]) * sr[c];
    a0 = fmaf(v, W[c*3+0], a0);
    a1 = fmaf(v, W[c*3+1], a1);
    a2 = fmaf(v, W[c*3+2], a2);
  }
  float inv = 1.f / sqrtf(a0*a0 + a1*a1 + a2*a2);
  int n = nb + lane;
  X[n*3+0] = a0 * inv;
  X[n*3+1] = a1 * inv;
  X[n*3+2] = a2 * inv;
}

// ------------- MMD -------------
__device__ inline float block_reduce_sum(float v) {
  #pragma unroll
  for (int o = 32; o > 0; o >>= 1) v += __shfl_down(v, o, 64);
  __shared__ float red[4];
  int lane = threadIdx.x & 63, w = threadIdx.x >> 6;
  if (lane == 0) red[w] = v;
  __syncthreads();
  float t = 0.f;
  if (threadIdx.x == 0) t = red[0] + red[1] + red[2] + red[3];
  return t;
}

__global__ __launch_bounds__(256) void kxx_kernel(
    const float* __restrict__ X, float* __restrict__ kxx)
{
  int b  = blockIdx.x >> 5;
  int nt = blockIdx.x & 31;
  const float* Xb = X + (size_t)b * NSAMP * 3;
  __shared__ float sx[192];
  if (threadIdx.x < 192) sx[threadIdx.x] = Xb[nt*192 + threadIdx.x];
  __syncthreads();
  float ps = 0.f;
  for (int it = 0; it < 8; it++) {
    int m = it*256 + threadIdx.x;
    float x0 = Xb[m*3+0], x1 = Xb[m*3+1], x2 = Xb[m*3+2];
    #pragma unroll
    for (int n = 0; n < 64; n++) {
      float d = x0*sx[n*3+0] + x1*sx[n*3+1] + x2*sx[n*3+2];
      ps += __expf(2.f*d - 2.f);
    }
  }
  float t = block_reduce_sum(ps);
  if (threadIdx.x == 0) atomicAdd(&kxx[b], t);
}

__global__ __launch_bounds__(256) void kxy_kernel(
    const float* __restrict__ X, YArr Y, float* __restrict__ kxy)
{
  int b = blockIdx.x;
  const float* Xb = X + (size_t)b * NSAMP * 3;
  float ps = 0.f;
  for (int it = 0; it < 8; it++) {
    int n = it*256 + threadIdx.x;
    float x0 = Xb[n*3+0], x1 = Xb[n*3+1], x2 = Xb[n*3+2];
    #pragma unroll
    for (int m = 0; m < 64; m++) {
      float d = x0*Y.v[m*3+0] + x1*Y.v[m*3+1] + x2*Y.v[m*3+2];
      ps += __expf(2.f*d - 2.f);
    }
  }
  float t = block_reduce_sum(ps);
  if (threadIdx.x == 0) kxy[b] = t;
}

__global__ void loss_kernel(const float* __restrict__ kxx,
                            const float* __restrict__ kxy,
                            float kyy, float* __restrict__ out)
{
  if (threadIdx.x == 0 && blockIdx.x == 0) {
    float s = 0.f;
    for (int b = 0; b < NBATCH; b++)
      s += kxx[b] * (1.0f/((float)NSAMP*(float)NSAMP))
         - 2.0f * kxy[b] * (1.0f/((float)NSAMP*64.0f));
    out[0] = s * (1.0f/NBATCH) + kyy;
  }
}

// ------------- launch -------------
extern "C" void kernel_launch(void* const* d_in, const int* in_sizes, int n_in,
                              void* d_out, int out_size, void* d_ws, size_t ws_size,
                              hipStream_t stream)
{
  const float* x    = (const float*)d_in[0];
  const int*   esrc = (const int*)  d_in[1];
  const int*   edst = (const int*)  d_in[2];
  const float* encW = (const float*)d_in[4];
  const float* encb = (const float*)d_in[5];
  const float* m1W  = (const float*)d_in[6];
  const float* m1b  = (const float*)d_in[7];
  const float* m2W  = (const float*)d_in[8];
  const float* m2b  = (const float*)d_in[9];
  const float* u1W  = (const float*)d_in[10];
  const float* u1b  = (const float*)d_in[11];
  const float* u2W  = (const float*)d_in[12];
  const float* u2b  = (const float*)d_in[13];
  const float* decW = (const float*)d_in[14];
  const float* decb = (const float*)d_in[15];
  float* out = (float*)d_out;

  const size_t NF = (size_t)NNODES * 64;
  float* u_buf  = (float*)d_ws;
  float* aggAll = u_buf + NF;          // 4 * NF
  float* Pbuf   = aggAll + 4*NF;
  float* Qbuf   = Pbuf + NF;
  float* Rbuf   = Qbuf + NF;
  float* statsA = Rbuf + NF;           // [4][1024]
  float* statsB = statsA + 4*1024;
  float* kxx    = statsB + 4*1024;
  float* kxy    = kxx + 16;
  int* icnt     = (int*)(kxy + 16);
  int* ioffs    = icnt + NNODES;
  int* icur     = ioffs + NNODES;
  int* psrc     = icur + NNODES;
  int* pdst     = psrc + NEDGES;
  ushort_t* us  = (ushort_t*)(pdst + NEDGES);
  ushort_t* wc_hi  = us;  us += 4*192*PK2;
  ushort_t* wc_lo  = us;  us += 4*192*PK2;
  ushort_t* w1b_hi = us;  us += 4*64*PK2;
  ushort_t* w1b_lo = us;  us += 4*64*PK2;
  ushort_t* w2e_hi = us;  us += 4*64*PK2;
  ushort_t* w2e_lo = us;  us += 4*64*PK2;
  ushort_t* w2n_hi = us;  us += 4*64*PK2;
  ushort_t* w2n_lo = us;  us += 4*64*PK2;

  float* X = out + 1;

  prep_weights_kernel<<<384, 256, 0, stream>>>(
      m1W, m2W, u1W, u2W,
      wc_hi, wc_lo, w1b_hi, w1b_lo, w2e_hi, w2e_lo, w2n_hi, w2n_lo);

  hipMemsetAsync(icnt, 0, NNODES * sizeof(int), stream);
  count_kernel<<<NEDGES/256, 256, 0, stream>>>(edst, icnt);
  scan_kernel<<<1, 1024, 0, stream>>>(icnt, ioffs, icur);
  fill_kernel<<<NEDGES/256, 256, 0, stream>>>(esrc, edst, icur, psrc, pdst);

  hipMemsetAsync(aggAll, 0, 4*NF*sizeof(float), stream);
  hipMemsetAsync(statsA, 0, 2*4*1024*sizeof(float), stream);

  for (int l = 0; l < 4; l++) {
    const ushort_t* wch = wc_hi + (size_t)l*192*PK2;
    const ushort_t* wcl = wc_lo + (size_t)l*192*PK2;
    if (l == 0)
      norm_pqr_kernel<0><<<512, 256, 0, stream>>>(
          x, nullptr, nullptr, encW, encb, wch, wcl, Pbuf, Qbuf, Rbuf);
    else
      norm_pqr_kernel<1><<<512, 256, 0, stream>>>(
          u_buf, statsA + (l-1)*1024, statsB + (l-1)*1024, nullptr, nullptr,
          wch, wcl, Pbuf, Qbuf, Rbuf);

    edge_fused_kernel<<<768, 256, 0, stream>>>(
        Pbuf, Qbuf, psrc, pdst, m1b + l*64,
        w2e_hi + (size_t)l*64*PK2, w2e_lo + (size_t)l*64*PK2, m2b + l*64,
        aggAll + (size_t)l*NF);

    node_mfma_kernel<<<512, 256, 0, stream>>>(
        aggAll + (size_t)l*NF, Rbuf,
        w1b_hi + (size_t)l*64*PK2, w1b_lo + (size_t)l*64*PK2, u1b + l*64,
        w2n_hi + (size_t)l*64*PK2, w2n_lo + (size_t)l*64*PK2, u2b + l*64,
        u_buf, statsA + l*1024, statsB + l*1024);
  }

  decoder_kernel<<<NNODES/64, 64, 0, stream>>>(
      u_buf, statsA + 3*1024, statsB + 3*1024, decW, decb, X);

  hipMemsetAsync(kxx, 0, 16 * sizeof(float), stream);
  kxx_kernel<<<NBATCH*32, 256, 0, stream>>>(X, kxx);

  YArr Y;
  {
    const double pi = 3.14159265358979323846;
    double phi = pi * (3.0 - sqrt(5.0));
    for (int i = 0; i < 64; i++) {
      double y  = 1.0 - 2.0 * (double)i / 63.0;
      double r  = sqrt(fmax(0.0, 1.0 - y*y));
      double th = phi * (double)i;
      Y.v[i*3+0] = (float)(cos(th) * r);
      Y.v[i*3+1] = (float)y;
      Y.v[i*3+2] = (float)(sin(th) * r);
    }
  }
  double kyy_acc = 0.0;
  for (int i = 0; i < 64; i++)
    for (int j = 0; j < 64; j++) {
      double d = (double)Y.v[i*3+0]*Y.v[j*3+0]
               + (double)Y.v[i*3+1]*Y.v[j*3+1]
               + (double)Y.v[i*3+2]*Y.v[j*3+2];
      kyy_acc += exp(2.0*d - 2.0);
    }
  float kyy = (float)(kyy_acc / 4096.0);

  kxy_kernel<<<NBATCH, 256, 0, stream>>>(X, Y, kxy);
  loss_kernel<<<1, 64, 0, stream>>>(kxx, kxy, kyy, out);
}